// Round 13
// baseline (310.388 us; speedup 1.0000x reference)
//
#include <hip/hip_runtime.h>
#include <hip/hip_fp16.h>

#define NN 50000
#define NE 800000
#define NG 512
#define DD 128
#define NCH 8                // column chunks (== XCDs); 16 cols each
#define NSB 64               // sub-bins == subpartitions (one wg each)
#define SUBN 782             // ceil(NN/NSB); 64*782 = 50048
#define SBCAP 14336          // per-sub-bin capacity (mean 12500, sigma 111)
#define NB1 512
#define NI4 (NE / 4)         // 200000 int4-quads
#define CH4 ((NI4 + NB1 - 1) / NB1)    // 391 quads per block

typedef __attribute__((ext_vector_type(8))) _Float16 f16x8;
typedef __attribute__((ext_vector_type(4))) float f32x4;
typedef int v4i __attribute__((ext_vector_type(4)));

// ---- P0: features f32 -> fp16, pre-scaled by out_norm, column-blocked
// layout xb[chunk][node][16] (chunk = col/16). Runs AFTER norms are built.
__global__ __launch_bounds__(256) void k_f2h(
    const float4* __restrict__ in, const float* __restrict__ out_norm,
    unsigned long long* __restrict__ xb, int nt) {
  int t = blockIdx.x * 256 + threadIdx.x;
  if (t >= nt) return;                  // nt = NN*16 (8 cols per thread)
  int row = t >> 4;
  int cg = t & 15;                      // 8-col group; cols c0 = cg*8
  int c0 = cg * 8;
  float w = out_norm[row];
  float4 v0 = in[(size_t)row * 32 + cg * 2];
  float4 v1 = in[(size_t)row * 32 + cg * 2 + 1];
  __half2 a = __floats2half2_rn(v0.x * w, v0.y * w);
  __half2 b = __floats2half2_rn(v0.z * w, v0.w * w);
  __half2 c = __floats2half2_rn(v1.x * w, v1.y * w);
  __half2 d = __floats2half2_rn(v1.z * w, v1.w * w);
  unsigned long long lo = ((unsigned long long)*(unsigned int*)&b << 32) | *(unsigned int*)&a;
  unsigned long long hi = ((unsigned long long)*(unsigned int*)&d << 32) | *(unsigned int*)&c;
  int chunk = c0 >> 4, off = c0 & 15;   // off in {0,8}
  unsigned long long* dst = xb + (((size_t)chunk * NN + row) * 16 + off) / 4;
  dst[0] = lo;
  dst[1] = hi;
}

// ---- W split (f32 -> fp16 hi + fp16 residual), MFMA B-fragment order.
__global__ __launch_bounds__(256) void k_wsplit2(
    const float* __restrict__ W1, const float* __restrict__ W2,
    _Float16* __restrict__ h1, _Float16* __restrict__ l1,
    _Float16* __restrict__ h2, _Float16* __restrict__ l2) {
  int b = blockIdx.x;
  const float* W = (b < 8) ? W1 : W2;
  _Float16* hi = (b < 8) ? h1 : h2;
  _Float16* lo = (b < 8) ? l1 : l2;
  int t = (b & 7) * 256 + threadIdx.x;   // 0..2047
  int lane = t & 63;
  int grp = t >> 6;        // nt*4+kk
  int kk = grp & 3;
  int nt = grp >> 2;
  int kbase = kk * 32 + ((lane >> 4) << 3);
  int c = nt * 16 + (lane & 15);
#pragma unroll
  for (int j = 0; j < 8; ++j) {
    float v = W[(kbase + j) * DD + c];
    _Float16 h = (_Float16)v;
    hi[t * 8 + j] = h;
    lo[t * 8 + j] = (_Float16)(v - (float)h);
  }
}

// ---- P1: bin edges into 64 sub-bins (dst-keyed (d,s) u64; src-keyed u16 local). ----
__global__ __launch_bounds__(256) void k_bin(
    const int* __restrict__ src, const int* __restrict__ dst,
    int* __restrict__ cur_d, int* __restrict__ cur_s,
    unsigned long long* __restrict__ byDst, unsigned short* __restrict__ bySrc) {
  __shared__ int cntd[NSB], cnts[NSB], based[NSB], bases[NSB];
  int i0 = blockIdx.x * CH4;
  int i1 = i0 + CH4; if (i1 > NI4) i1 = NI4;
  int tid = threadIdx.x;
  if (tid < NSB) { cntd[tid] = 0; cnts[tid] = 0; }
  __syncthreads();
  const v4i* s4 = (const v4i*)src;
  const v4i* d4 = (const v4i*)dst;
  for (int i = i0 + tid; i < i1; i += 256) {
    v4i sv = __builtin_nontemporal_load(&s4[i]);
    v4i dv = __builtin_nontemporal_load(&d4[i]);
#pragma unroll
    for (int k = 0; k < 4; ++k) {
      atomicAdd(&cntd[dv[k] / SUBN], 1);
      atomicAdd(&cnts[sv[k] / SUBN], 1);
    }
  }
  __syncthreads();
  if (tid < NSB) {
    based[tid] = atomicAdd(&cur_d[tid], cntd[tid]);
    cntd[tid] = 0;
  } else if (tid < 2 * NSB) {
    int b = tid - NSB;
    bases[b] = atomicAdd(&cur_s[b], cnts[b]);
    cnts[b] = 0;
  }
  __syncthreads();
  for (int i = i0 + tid; i < i1; i += 256) {
    v4i sv = __builtin_nontemporal_load(&s4[i]);
    v4i dv = __builtin_nontemporal_load(&d4[i]);
#pragma unroll
    for (int k = 0; k < 4; ++k) {
      int d = dv[k], s = sv[k];
      int bd = d / SUBN;
      int pd = based[bd] + atomicAdd(&cntd[bd], 1);
      if (pd < SBCAP) byDst[(size_t)bd * SBCAP + pd] = ((unsigned long long)(unsigned)d << 32) | (unsigned)s;
      int bs = s / SUBN;
      int ps = bases[bs] + atomicAdd(&cnts[bs], 1);
      if (ps < SBCAP) bySrc[(size_t)bs * SBCAP + ps] = (unsigned short)(s - bs * SUBN);
    }
  }
}

// ---- P2a: per-sub-bin histogram + scan + CSR scatter. No global atomics. ----
__global__ __launch_bounds__(1024) void k_csr_dst(
    const unsigned long long* __restrict__ byDst, const int* __restrict__ cur_d,
    int* __restrict__ csr, int* __restrict__ row_start, int* __restrict__ deg_in) {
  int q = blockIdx.x;
  int nlo = q * SUBN;
  int nhi = nlo + SUBN; if (nhi > NN) nhi = NN;
  int nloc = nhi - nlo;
  __shared__ int hist[SUBN];
  __shared__ int wsum[16];
  int tid = threadIdx.x;
  for (int i = tid; i < SUBN; i += 1024) hist[i] = 0;
  __syncthreads();
  int m = cur_d[q];
  if (m > SBCAP) m = SBCAP;
  const unsigned long long* bine = byDst + (size_t)q * SBCAP;
  for (int i = tid; i < m; i += 1024) {
    int l = (int)(bine[i] >> 32) - nlo;
    if (l >= 0 && l < nloc) atomicAdd(&hist[l], 1);
  }
  __syncthreads();
  int v = (tid < SUBN) ? hist[tid] : 0;
  int incl = v;
  int lane = tid & 63;
#pragma unroll
  for (int off = 1; off < 64; off <<= 1) {
    int t2 = __shfl_up(incl, off);
    if (lane >= off) incl += t2;
  }
  int wid = tid >> 6;
  if (lane == 63) wsum[wid] = incl;
  __syncthreads();
  if (tid == 0) {
    int run = 0;
    for (int i = 0; i < 16; ++i) { int t = wsum[i]; wsum[i] = run; run += t; }
  }
  __syncthreads();
  int excl = incl - v + wsum[wid];
  if (tid < nloc) {
    deg_in[nlo + tid] = v;
    row_start[nlo + tid] = q * SBCAP + excl;
  }
  __syncthreads();
  if (tid < SUBN) hist[tid] = excl;   // scatter cursor
  __syncthreads();
  for (int i = tid; i < m; i += 1024) {
    unsigned long long p = bine[i];
    int l = (int)(p >> 32) - nlo;
    if (l >= 0 && l < nloc) {
      int pos = atomicAdd(&hist[l], 1);
      if (pos < SBCAP) csr[(size_t)q * SBCAP + pos] = (int)(unsigned)p;
    }
  }
}

// ---- P2b: src histogram (u16 local ids) -> out_norm; also in_norm from deg_in ----
__global__ __launch_bounds__(1024) void k_deg_src_norm(
    const unsigned short* __restrict__ bySrc, const int* __restrict__ cur_s,
    const int* __restrict__ deg_in,
    float* __restrict__ out_norm, float* __restrict__ in_norm) {
  int q = blockIdx.x;
  int nlo = q * SUBN;
  int nhi = nlo + SUBN; if (nhi > NN) nhi = NN;
  int nloc = nhi - nlo;
  __shared__ int hist[SUBN];
  int tid = threadIdx.x;
  for (int i = tid; i < SUBN; i += 1024) hist[i] = 0;
  __syncthreads();
  int m = cur_s[q];
  if (m > SBCAP) m = SBCAP;
  const unsigned short* bine = bySrc + (size_t)q * SBCAP;
  for (int i = tid; i < m; i += 1024) {
    atomicAdd(&hist[bine[i]], 1);
  }
  __syncthreads();
  for (int i = tid; i < nloc; i += 1024) {
    int od = hist[i];
    out_norm[nlo + i] = od > 0 ? rsqrtf((float)od) : 0.f;
    int idg = deg_in[nlo + i];
    in_norm[nlo + i] = idg > 0 ? rsqrtf((float)idg) : 0.f;
  }
}

// ---- aggregation, XCD column-sharded + 4-deep MLP ----
// chunk = blockIdx&7 (XCD-local shard, 1.6 MB, L2-resident). Wave per (node,chunk).
// 32 edge ids batched per iteration (lanes 0-31, one load), then 4 INDEPENDENT
// gathers per lane (8-lane col groups x 4 sub-batches) -> 4 loads in flight.
__global__ __launch_bounds__(256) void k_agg(
    const __half2* __restrict__ xb, const int* __restrict__ csr,
    const int* __restrict__ row_start, const int* __restrict__ deg_in,
    float2* __restrict__ agg) {
  int chunk = blockIdx.x & 7;
  int node = (blockIdx.x >> 3) * 4 + (threadIdx.x >> 6);
  int lane = threadIdx.x & 63;
  if (node >= NN) return;
  int n = deg_in[node];
  const int* bk = csr + row_start[node];
  const __half2* xc = xb + (size_t)chunk * NN * 8;
  int g = lane >> 3, c = lane & 7;
  float2 a0 = {0.f, 0.f}, a1 = {0.f, 0.f}, a2 = {0.f, 0.f}, a3 = {0.f, 0.f};
  for (int j = 0; j < n; j += 32) {
    int s = (lane < 32 && j + lane < n) ? bk[j + lane] : -1;
    int s0 = __shfl(s, g);
    int s1 = __shfl(s, 8 + g);
    int s2 = __shfl(s, 16 + g);
    int s3 = __shfl(s, 24 + g);
    if (s0 >= 0) { float2 v = __half22float2(xc[(size_t)s0 * 8 + c]); a0.x += v.x; a0.y += v.y; }
    if (s1 >= 0) { float2 v = __half22float2(xc[(size_t)s1 * 8 + c]); a1.x += v.x; a1.y += v.y; }
    if (s2 >= 0) { float2 v = __half22float2(xc[(size_t)s2 * 8 + c]); a2.x += v.x; a2.y += v.y; }
    if (s3 >= 0) { float2 v = __half22float2(xc[(size_t)s3 * 8 + c]); a3.x += v.x; a3.y += v.y; }
  }
  a0.x += a1.x + a2.x + a3.x;
  a0.y += a1.y + a2.y + a3.y;
  a0.x += __shfl_xor(a0.x, 8);  a0.y += __shfl_xor(a0.y, 8);
  a0.x += __shfl_xor(a0.x, 16); a0.y += __shfl_xor(a0.y, 16);
  a0.x += __shfl_xor(a0.x, 32); a0.y += __shfl_xor(a0.y, 32);
  if (lane < 8) agg[((size_t)chunk * NN + node) * 8 + lane] = a0;
}

// ---- MFMA GEMM: Y[i][c] = act(in_norm[i] * (A@W)[i][c] + b[c]) ----
// A in column-blocked layout [chunk][node][16] f32. Split-fp16 3-MFMA product.
// HOUT: store h * out_norm (pre-scaled for next layer's gather), blocked fp16.
// POOL: per-row logits z[row] = y@Wc via 16-lane butterfly, dense store.
template <bool RELU, bool HOUT, bool POOL>
__global__ __launch_bounds__(256, 4) void k_gemm_mfma(
    const float* __restrict__ A, const float* __restrict__ in_norm,
    const float* __restrict__ out_norm,
    const _Float16* __restrict__ Whi, const _Float16* __restrict__ Wlo,
    const float* __restrict__ bias, void* __restrict__ Yv,
    const float* __restrict__ Wc, float2* __restrict__ z) {
  int tid = threadIdx.x;
  int wid = tid >> 6, lane = tid & 63;
  int row0 = blockIdx.x * 64 + wid * 16;
  int ar = row0 + (lane & 15);
  bool rv = ar < NN;
  f16x8 ahi[4], alo[4];
#pragma unroll
  for (int kk = 0; kk < 4; ++kk) {
    f32x4 u0 = {0.f, 0.f, 0.f, 0.f}, u1 = {0.f, 0.f, 0.f, 0.f};
    int cb = kk * 32 + ((lane >> 4) << 3);
    if (rv) {
      const f32x4* ap = (const f32x4*)(A + ((size_t)(cb >> 4) * NN + ar) * 16 + (cb & 15));
      u0 = __builtin_nontemporal_load(ap);
      u1 = __builtin_nontemporal_load(ap + 1);
    }
    float v[8] = {u0.x, u0.y, u0.z, u0.w, u1.x, u1.y, u1.z, u1.w};
#pragma unroll
    for (int j = 0; j < 8; ++j) {
      _Float16 h = (_Float16)v[j];
      ahi[kk][j] = h;
      alo[kk][j] = (_Float16)(v[j] - (float)h);
    }
  }
  f32x4 acc[8];
#pragma unroll
  for (int nt = 0; nt < 8; ++nt) acc[nt] = (f32x4){0.f, 0.f, 0.f, 0.f};
#pragma unroll
  for (int nt = 0; nt < 8; ++nt) {
#pragma unroll
    for (int kk = 0; kk < 4; ++kk) {
      f16x8 bh = *(const f16x8*)&Whi[(((nt * 4 + kk) * 64) + lane) * 8];
      f16x8 bl = *(const f16x8*)&Wlo[(((nt * 4 + kk) * 64) + lane) * 8];
      acc[nt] = __builtin_amdgcn_mfma_f32_16x16x32_f16(ahi[kk], bh, acc[nt], 0, 0, 0);
      acc[nt] = __builtin_amdgcn_mfma_f32_16x16x32_f16(ahi[kk], bl, acc[nt], 0, 0, 0);
      acc[nt] = __builtin_amdgcn_mfma_f32_16x16x32_f16(alo[kk], bh, acc[nt], 0, 0, 0);
    }
  }
  int r4 = (lane >> 4) * 4;
  int c0 = lane & 15;
  if (POOL) {
    float wc0[8], wc1[8];
#pragma unroll
    for (int nt = 0; nt < 8; ++nt) {
      int col = nt * 16 + c0;
      wc0[nt] = Wc[col * 2 + 0];
      wc1[nt] = Wc[col * 2 + 1];
    }
#pragma unroll
    for (int reg = 0; reg < 4; ++reg) {
      int row = row0 + r4 + reg;
      float inm = (row < NN) ? in_norm[row] : 0.f;
      float v0 = 0.f, v1 = 0.f;
#pragma unroll
      for (int nt = 0; nt < 8; ++nt) {
        int col = nt * 16 + c0;
        float y = acc[nt][reg] * inm + bias[col];
        if (RELU) y = fmaxf(y, 0.f);
        v0 += y * wc0[nt];
        v1 += y * wc1[nt];
      }
#pragma unroll
      for (int off = 1; off < 16; off <<= 1) {
        v0 += __shfl_xor(v0, off);
        v1 += __shfl_xor(v1, off);
      }
      if (row < NN && c0 == 0) {
        z[row] = make_float2(v0, v1);
      }
    }
  } else {
#pragma unroll
    for (int reg = 0; reg < 4; ++reg) {
      int row = row0 + r4 + reg;
      if (row < NN) {
        float inm = in_norm[row];
        float onm = HOUT ? out_norm[row] : 1.f;
#pragma unroll
        for (int nt = 0; nt < 8; ++nt) {
          int col = nt * 16 + c0;
          float y = acc[nt][reg] * inm + bias[col];
          if (RELU) y = fmaxf(y, 0.f);
          if (HOUT) {
            // store pre-scaled for next layer's gather, column-blocked
            ((__half*)Yv)[((size_t)nt * NN + row) * 16 + c0] = __float2half(y * onm);
          } else {
            ((float*)Yv)[(size_t)row * DD + col] = y;
          }
        }
      }
    }
  }
}

// ---- pool: one wave per graph; segment-mean of z + bias -> out ----
__global__ __launch_bounds__(256) void k_pool2(
    const float* __restrict__ z, const int* __restrict__ gid,
    const float* __restrict__ bc, float* __restrict__ out) {
  int g = blockIdx.x * 4 + (threadIdx.x >> 6);
  int lane = threadIdx.x & 63;
  if (g >= NG) return;
  int lo, hi;
  { int a = 0, b = NN; while (a < b) { int m = (a + b) >> 1; if (gid[m] < g) a = m + 1; else b = m; } lo = a; }
  { int a = lo, b = NN; while (a < b) { int m = (a + b) >> 1; if (gid[m] <= g) a = m + 1; else b = m; } hi = a; }
  float s = 0.f;
  int col = lane & 1;
  for (int i = lo + (lane >> 1); i < hi; i += 32) s += z[i * 2 + col];
#pragma unroll
  for (int off = 32; off >= 2; off >>= 1) s += __shfl_down(s, off);
  if (lane < 2) {
    int n = hi - lo;
    out[g * 2 + lane] = s / (float)(n > 0 ? n : 1) + bc[lane];
  }
}

extern "C" void kernel_launch(void* const* d_in, const int* in_sizes, int n_in,
                              void* d_out, int out_size, void* d_ws, size_t ws_size,
                              hipStream_t stream) {
  const float* features = (const float*)d_in[0];
  const int* src = (const int*)d_in[1];
  const int* dst = (const int*)d_in[2];
  const int* gid = (const int*)d_in[3];
  const float* W1 = (const float*)d_in[4];
  const float* b1 = (const float*)d_in[5];
  const float* W2 = (const float*)d_in[6];
  const float* b2 = (const float*)d_in[7];
  const float* Wc = (const float*)d_in[8];
  const float* bc = (const float*)d_in[9];
  float* out = (float*)d_out;

  char* ws = (char*)d_ws;
  size_t off = 0;
  auto take = [&](size_t bytes) {
    char* p = ws + off;
    off = (off + bytes + 255) & ~(size_t)255;
    return p;
  };
  int* cur_d      = (int*)take(NSB * 4);
  int* cur_s      = (int*)take(NSB * 4);
  int* deg_in     = (int*)take((size_t)NN * 4);
  float* out_nrm  = (float*)take((size_t)NN * 4);
  float* in_nrm   = (float*)take((size_t)NN * 4);
  int* row_start  = (int*)take((size_t)NN * 4);
  float* zbuf     = (float*)take((size_t)NN * 2 * 4);
  unsigned long long* byDst = (unsigned long long*)take((size_t)NSB * SBCAP * 8);
  unsigned short* bySrc = (unsigned short*)take((size_t)NSB * SBCAP * 2);
  int* csr        = (int*)take((size_t)NSB * SBCAP * 4);
  __half* xh      = (__half*)take((size_t)NN * DD * 2);
  __half* h1h     = (__half*)take((size_t)NN * DD * 2);
  float* bufA     = (float*)take((size_t)NN * DD * 4);
  _Float16* w1hi  = (_Float16*)take((size_t)DD * DD * 2);
  _Float16* w1lo  = (_Float16*)take((size_t)DD * DD * 2);
  _Float16* w2hi  = (_Float16*)take((size_t)DD * DD * 2);
  _Float16* w2lo  = (_Float16*)take((size_t)DD * DD * 2);

  hipMemsetAsync(cur_d, 0, NSB * 4, stream);
  hipMemsetAsync(cur_s, 0, NSB * 4, stream);

  k_wsplit2<<<16, 256, 0, stream>>>(W1, W2, w1hi, w1lo, w2hi, w2lo);
  k_bin<<<NB1, 256, 0, stream>>>(src, dst, cur_d, cur_s, byDst, bySrc);
  k_csr_dst<<<NSB, 1024, 0, stream>>>(byDst, cur_d, csr, row_start, deg_in);
  k_deg_src_norm<<<NSB, 1024, 0, stream>>>(bySrc, cur_s, deg_in, out_nrm, in_nrm);
  // f2h needs out_norm -> after norms
  k_f2h<<<(NN * 16 + 255) / 256, 256, 0, stream>>>(
      (const float4*)features, out_nrm, (unsigned long long*)xh, NN * 16);

  // layer 1: agg(xh) -> bufA (blocked) ; mfma-gemm+relu -> h1h (fp16, blocked, pre-scaled)
  k_agg<<<((NN + 3) / 4) * NCH, 256, 0, stream>>>(
      (const __half2*)xh, csr, row_start, deg_in, (float2*)bufA);
  k_gemm_mfma<true, true, false><<<(NN + 63) / 64, 256, 0, stream>>>(
      bufA, in_nrm, out_nrm, w1hi, w1lo, b1, h1h, nullptr, nullptr);

  // layer 2: agg(h1h) -> bufA ; mfma-gemm + fused classifier logits -> zbuf
  k_agg<<<((NN + 3) / 4) * NCH, 256, 0, stream>>>(
      (const __half2*)h1h, csr, row_start, deg_in, (float2*)bufA);
  k_gemm_mfma<false, false, true><<<(NN + 63) / 64, 256, 0, stream>>>(
      bufA, in_nrm, out_nrm, w2hi, w2lo, b2, nullptr, Wc, (float2*)zbuf);

  // segment mean-pool + bias
  k_pool2<<<(NG + 3) / 4, 256, 0, stream>>>(zbuf, gid, bc, out);
}

// Round 14
// 139.467 us; speedup vs baseline: 2.2255x; 2.2255x over previous
//
#include <hip/hip_runtime.h>
#include <hip/hip_fp16.h>

#define NN 50000
#define NE 800000
#define NG 512
#define DD 128
#define NSB 64               // sub-bins == subpartitions (one wg each)
#define SUBN 782             // ceil(NN/NSB); 64*782 = 50048
#define SBCAP 14336          // per-sub-bin capacity (mean 12500, sigma 111)
#define NB1 512
#define NI4 (NE / 4)         // 200000 int4-quads
#define CH4 ((NI4 + NB1 - 1) / NB1)    // 391 quads per block

typedef __attribute__((ext_vector_type(8))) _Float16 f16x8;
typedef __attribute__((ext_vector_type(4))) float f32x4;
typedef int v4i __attribute__((ext_vector_type(4)));

// ---- P0: features f32 -> fp16, pre-scaled by out_norm (row-major) ----
__global__ __launch_bounds__(256) void k_f2h(
    const float4* __restrict__ in, const float* __restrict__ out_norm,
    uint2* __restrict__ out, int n4) {
  int i = blockIdx.x * 256 + threadIdx.x;
  if (i >= n4) return;                  // n4 = NN*32 (4 cols per thread)
  float w = out_norm[i >> 5];
  float4 v = in[i];
  __half2 a = __floats2half2_rn(v.x * w, v.y * w);
  __half2 b = __floats2half2_rn(v.z * w, v.w * w);
  uint2 o;
  o.x = *(unsigned int*)&a;
  o.y = *(unsigned int*)&b;
  out[i] = o;
}

// ---- W1 split (f32 -> fp16 hi + fp16 residual), MFMA B-fragment order:
// idx = ((nt*4+kk)*64 + lane)*8 + j holds W[kk*32+(lane>>4)*8+j][nt*16+(lane&15)].
__global__ __launch_bounds__(256) void k_wsplit(
    const float* __restrict__ W, _Float16* __restrict__ hi, _Float16* __restrict__ lo) {
  int t = blockIdx.x * 256 + threadIdx.x;   // 0..2047
  int lane = t & 63;
  int grp = t >> 6;        // nt*4+kk
  int kk = grp & 3;
  int nt = grp >> 2;
  int kbase = kk * 32 + ((lane >> 4) << 3);
  int c = nt * 16 + (lane & 15);
#pragma unroll
  for (int j = 0; j < 8; ++j) {
    float v = W[(kbase + j) * DD + c];
    _Float16 h = (_Float16)v;
    hi[t * 8 + j] = h;
    lo[t * 8 + j] = (_Float16)(v - (float)h);
  }
}

// ---- W2c = W2 @ Wc  [128][2] ; zc = b2 @ Wc + bc [2] ----
__global__ __launch_bounds__(256) void k_w2c(
    const float* __restrict__ W2, const float* __restrict__ Wc,
    const float* __restrict__ b2, const float* __restrict__ bc,
    float* __restrict__ W2c, float* __restrict__ zc) {
  int t = threadIdx.x;          // 256 threads: row = t>>1, cc = t&1
  int row = t >> 1, cc = t & 1;
  float s = 0.f;
#pragma unroll 8
  for (int c = 0; c < DD; ++c) s += W2[row * DD + c] * Wc[c * 2 + cc];
  W2c[row * 2 + cc] = s;
  if (t < 2) {
    float b = 0.f;
    for (int c = 0; c < DD; ++c) b += b2[c] * Wc[c * 2 + t];
    zc[t] = b + bc[t];
  }
}

// ---- P1: bin edges into 64 sub-bins (dst-keyed (d,s) u64; src-keyed u16 local). ----
__global__ __launch_bounds__(256) void k_bin(
    const int* __restrict__ src, const int* __restrict__ dst,
    int* __restrict__ cur_d, int* __restrict__ cur_s,
    unsigned long long* __restrict__ byDst, unsigned short* __restrict__ bySrc) {
  __shared__ int cntd[NSB], cnts[NSB], based[NSB], bases[NSB];
  int i0 = blockIdx.x * CH4;
  int i1 = i0 + CH4; if (i1 > NI4) i1 = NI4;
  int tid = threadIdx.x;
  if (tid < NSB) { cntd[tid] = 0; cnts[tid] = 0; }
  __syncthreads();
  const v4i* s4 = (const v4i*)src;
  const v4i* d4 = (const v4i*)dst;
  for (int i = i0 + tid; i < i1; i += 256) {
    v4i sv = __builtin_nontemporal_load(&s4[i]);
    v4i dv = __builtin_nontemporal_load(&d4[i]);
#pragma unroll
    for (int k = 0; k < 4; ++k) {
      atomicAdd(&cntd[dv[k] / SUBN], 1);
      atomicAdd(&cnts[sv[k] / SUBN], 1);
    }
  }
  __syncthreads();
  if (tid < NSB) {
    based[tid] = atomicAdd(&cur_d[tid], cntd[tid]);
    cntd[tid] = 0;
  } else if (tid < 2 * NSB) {
    int b = tid - NSB;
    bases[b] = atomicAdd(&cur_s[b], cnts[b]);
    cnts[b] = 0;
  }
  __syncthreads();
  for (int i = i0 + tid; i < i1; i += 256) {
    v4i sv = __builtin_nontemporal_load(&s4[i]);
    v4i dv = __builtin_nontemporal_load(&d4[i]);
#pragma unroll
    for (int k = 0; k < 4; ++k) {
      int d = dv[k], s = sv[k];
      int bd = d / SUBN;
      int pd = based[bd] + atomicAdd(&cntd[bd], 1);
      if (pd < SBCAP) byDst[(size_t)bd * SBCAP + pd] = ((unsigned long long)(unsigned)d << 32) | (unsigned)s;
      int bs = s / SUBN;
      int ps = bases[bs] + atomicAdd(&cnts[bs], 1);
      if (ps < SBCAP) bySrc[(size_t)bs * SBCAP + ps] = (unsigned short)(s - bs * SUBN);
    }
  }
}

// ---- P2a: per-sub-bin histogram + scan + CSR scatter. No global atomics. ----
__global__ __launch_bounds__(1024) void k_csr_dst(
    const unsigned long long* __restrict__ byDst, const int* __restrict__ cur_d,
    int* __restrict__ csr, int* __restrict__ row_start, int* __restrict__ deg_in) {
  int q = blockIdx.x;
  int nlo = q * SUBN;
  int nhi = nlo + SUBN; if (nhi > NN) nhi = NN;
  int nloc = nhi - nlo;
  __shared__ int hist[SUBN];
  __shared__ int wsum[16];
  int tid = threadIdx.x;
  for (int i = tid; i < SUBN; i += 1024) hist[i] = 0;
  __syncthreads();
  int m = cur_d[q];
  if (m > SBCAP) m = SBCAP;
  const unsigned long long* bine = byDst + (size_t)q * SBCAP;
  for (int i = tid; i < m; i += 1024) {
    int l = (int)(bine[i] >> 32) - nlo;
    if (l >= 0 && l < nloc) atomicAdd(&hist[l], 1);
  }
  __syncthreads();
  int v = (tid < SUBN) ? hist[tid] : 0;
  int incl = v;
  int lane = tid & 63;
#pragma unroll
  for (int off = 1; off < 64; off <<= 1) {
    int t2 = __shfl_up(incl, off);
    if (lane >= off) incl += t2;
  }
  int wid = tid >> 6;
  if (lane == 63) wsum[wid] = incl;
  __syncthreads();
  if (tid == 0) {
    int run = 0;
    for (int i = 0; i < 16; ++i) { int t = wsum[i]; wsum[i] = run; run += t; }
  }
  __syncthreads();
  int excl = incl - v + wsum[wid];
  if (tid < nloc) {
    deg_in[nlo + tid] = v;
    row_start[nlo + tid] = q * SBCAP + excl;
  }
  __syncthreads();
  if (tid < SUBN) hist[tid] = excl;   // scatter cursor
  __syncthreads();
  for (int i = tid; i < m; i += 1024) {
    unsigned long long p = bine[i];
    int l = (int)(p >> 32) - nlo;
    if (l >= 0 && l < nloc) {
      int pos = atomicAdd(&hist[l], 1);
      if (pos < SBCAP) csr[(size_t)q * SBCAP + pos] = (int)(unsigned)p;
    }
  }
}

// ---- P2b: src histogram (u16 local ids) -> out_norm; also in_norm from deg_in ----
__global__ __launch_bounds__(1024) void k_deg_src_norm(
    const unsigned short* __restrict__ bySrc, const int* __restrict__ cur_s,
    const int* __restrict__ deg_in,
    float* __restrict__ out_norm, float* __restrict__ in_norm) {
  int q = blockIdx.x;
  int nlo = q * SUBN;
  int nhi = nlo + SUBN; if (nhi > NN) nhi = NN;
  int nloc = nhi - nlo;
  __shared__ int hist[SUBN];
  int tid = threadIdx.x;
  for (int i = tid; i < SUBN; i += 1024) hist[i] = 0;
  __syncthreads();
  int m = cur_s[q];
  if (m > SBCAP) m = SBCAP;
  const unsigned short* bine = bySrc + (size_t)q * SBCAP;
  for (int i = tid; i < m; i += 1024) {
    atomicAdd(&hist[bine[i]], 1);
  }
  __syncthreads();
  for (int i = tid; i < nloc; i += 1024) {
    int od = hist[i];
    out_norm[nlo + i] = od > 0 ? rsqrtf((float)od) : 0.f;
    int idg = deg_in[nlo + i];
    in_norm[nlo + i] = idg > 0 ? rsqrtf((float)idg) : 0.f;
  }
}

// ---- aggregation (layer 1): one wave per dst node, fp16 pre-scaled gather,
// f32 accumulate, 4-deep MLP. (r9 structure, minus the norm weight.) ----
__global__ __launch_bounds__(256) void k_agg(
    const __half* __restrict__ x, const int* __restrict__ csr,
    const int* __restrict__ row_start, const int* __restrict__ deg_in,
    float* __restrict__ agg) {
  int node = blockIdx.x * 4 + (threadIdx.x >> 6);
  int lane = threadIdx.x & 63;
  if (node >= NN) return;
  int n = deg_in[node];
  const int* bk = csr + row_start[node];
  const __half2* xv = (const __half2*)x;
  float2 a0 = {0.f, 0.f}, a1 = {0.f, 0.f}, a2 = {0.f, 0.f}, a3 = {0.f, 0.f};
  for (int c0 = 0; c0 < n; c0 += 64) {
    int nn = n - c0; if (nn > 64) nn = 64;
    int sl = (lane < nn) ? bk[c0 + lane] : 0;
    int j = 0;
    for (; j + 4 <= nn; j += 4) {
      int s0 = __shfl(sl, j + 0), s1 = __shfl(sl, j + 1);
      int s2 = __shfl(sl, j + 2), s3 = __shfl(sl, j + 3);
      float2 v0 = __half22float2(xv[(size_t)s0 * 64 + lane]);
      float2 v1 = __half22float2(xv[(size_t)s1 * 64 + lane]);
      float2 v2 = __half22float2(xv[(size_t)s2 * 64 + lane]);
      float2 v3 = __half22float2(xv[(size_t)s3 * 64 + lane]);
      a0.x += v0.x; a0.y += v0.y;
      a1.x += v1.x; a1.y += v1.y;
      a2.x += v2.x; a2.y += v2.y;
      a3.x += v3.x; a3.y += v3.y;
    }
    for (; j < nn; ++j) {
      int s0 = __shfl(sl, j);
      float2 v0 = __half22float2(xv[(size_t)s0 * 64 + lane]);
      a0.x += v0.x; a0.y += v0.y;
    }
  }
  a0.x += a1.x + a2.x + a3.x;
  a0.y += a1.y + a2.y + a3.y;
  ((float2*)agg)[(size_t)node * 64 + lane] = a0;
}

// ---- layer-1 MFMA GEMM + fused layer-2 projection ----
// h1 = relu(in_norm*(A@W1) + b1)   (in registers only, never stored)
// p[row] = out_norm[row] * (h1 @ W2c)   [2 floats per row]
__global__ __launch_bounds__(256, 4) void k_gemm1(
    const float* __restrict__ A, const float* __restrict__ in_norm,
    const float* __restrict__ out_norm,
    const _Float16* __restrict__ Whi, const _Float16* __restrict__ Wlo,
    const float* __restrict__ bias, const float* __restrict__ W2c,
    float2* __restrict__ p) {
  int tid = threadIdx.x;
  int wid = tid >> 6, lane = tid & 63;
  int row0 = blockIdx.x * 64 + wid * 16;
  int ar = row0 + (lane & 15);
  bool rv = ar < NN;
  f16x8 ahi[4], alo[4];
#pragma unroll
  for (int kk = 0; kk < 4; ++kk) {
    f32x4 u0 = {0.f, 0.f, 0.f, 0.f}, u1 = {0.f, 0.f, 0.f, 0.f};
    if (rv) {
      const f32x4* ap = (const f32x4*)(A + (size_t)ar * DD + kk * 32 + ((lane >> 4) << 3));
      u0 = __builtin_nontemporal_load(ap);
      u1 = __builtin_nontemporal_load(ap + 1);
    }
    float v[8] = {u0.x, u0.y, u0.z, u0.w, u1.x, u1.y, u1.z, u1.w};
#pragma unroll
    for (int j = 0; j < 8; ++j) {
      _Float16 h = (_Float16)v[j];
      ahi[kk][j] = h;
      alo[kk][j] = (_Float16)(v[j] - (float)h);
    }
  }
  f32x4 acc[8];
#pragma unroll
  for (int nt = 0; nt < 8; ++nt) acc[nt] = (f32x4){0.f, 0.f, 0.f, 0.f};
#pragma unroll
  for (int nt = 0; nt < 8; ++nt) {
#pragma unroll
    for (int kk = 0; kk < 4; ++kk) {
      f16x8 bh = *(const f16x8*)&Whi[(((nt * 4 + kk) * 64) + lane) * 8];
      f16x8 bl = *(const f16x8*)&Wlo[(((nt * 4 + kk) * 64) + lane) * 8];
      acc[nt] = __builtin_amdgcn_mfma_f32_16x16x32_f16(ahi[kk], bh, acc[nt], 0, 0, 0);
      acc[nt] = __builtin_amdgcn_mfma_f32_16x16x32_f16(ahi[kk], bl, acc[nt], 0, 0, 0);
      acc[nt] = __builtin_amdgcn_mfma_f32_16x16x32_f16(alo[kk], bh, acc[nt], 0, 0, 0);
    }
  }
  int r4 = (lane >> 4) * 4;
  int c0 = lane & 15;
  float wc0[8], wc1[8], bv[8];
#pragma unroll
  for (int nt = 0; nt < 8; ++nt) {
    int col = nt * 16 + c0;
    wc0[nt] = W2c[col * 2 + 0];
    wc1[nt] = W2c[col * 2 + 1];
    bv[nt] = bias[col];
  }
#pragma unroll
  for (int reg = 0; reg < 4; ++reg) {
    int row = row0 + r4 + reg;
    float inm = (row < NN) ? in_norm[row] : 0.f;
    float v0 = 0.f, v1 = 0.f;
#pragma unroll
    for (int nt = 0; nt < 8; ++nt) {
      float y = acc[nt][reg] * inm + bv[nt];
      y = fmaxf(y, 0.f);
      v0 += y * wc0[nt];
      v1 += y * wc1[nt];
    }
#pragma unroll
    for (int off = 1; off < 16; off <<= 1) {
      v0 += __shfl_xor(v0, off);
      v1 += __shfl_xor(v1, off);
    }
    if (row < NN && c0 == 0) {
      float onm = out_norm[row];
      p[row] = make_float2(v0 * onm, v1 * onm);
    }
  }
}

// ---- layer-2 aggregation on 2-dim projections: z[i] = in_norm[i] * sum p[nbr] ----
__global__ __launch_bounds__(256) void k_agg2(
    const float2* __restrict__ p, const int* __restrict__ csr,
    const int* __restrict__ row_start, const int* __restrict__ deg_in,
    const float* __restrict__ in_norm, float2* __restrict__ z) {
  int i = blockIdx.x * 256 + threadIdx.x;
  if (i >= NN) return;
  int n = deg_in[i];
  const int* bk = csr + row_start[i];
  float2 s0 = {0.f, 0.f}, s1 = {0.f, 0.f}, s2 = {0.f, 0.f}, s3 = {0.f, 0.f};
  int j = 0;
  for (; j + 4 <= n; j += 4) {
    int i0 = bk[j], i1 = bk[j + 1], i2 = bk[j + 2], i3 = bk[j + 3];
    float2 q0 = p[i0], q1 = p[i1], q2 = p[i2], q3 = p[i3];
    s0.x += q0.x; s0.y += q0.y;
    s1.x += q1.x; s1.y += q1.y;
    s2.x += q2.x; s2.y += q2.y;
    s3.x += q3.x; s3.y += q3.y;
  }
  for (; j < n; ++j) {
    float2 q = p[bk[j]];
    s0.x += q.x; s0.y += q.y;
  }
  s0.x += s1.x + s2.x + s3.x;
  s0.y += s1.y + s2.y + s3.y;
  float inm = in_norm[i];
  z[i] = make_float2(s0.x * inm, s0.y * inm);
}

// ---- pool: one wave per graph; segment-mean of z + zc -> out ----
__global__ __launch_bounds__(256) void k_pool2(
    const float* __restrict__ z, const int* __restrict__ gid,
    const float* __restrict__ zc, float* __restrict__ out) {
  int g = blockIdx.x * 4 + (threadIdx.x >> 6);
  int lane = threadIdx.x & 63;
  if (g >= NG) return;
  int lo, hi;
  { int a = 0, b = NN; while (a < b) { int m = (a + b) >> 1; if (gid[m] < g) a = m + 1; else b = m; } lo = a; }
  { int a = lo, b = NN; while (a < b) { int m = (a + b) >> 1; if (gid[m] <= g) a = m + 1; else b = m; } hi = a; }
  float s = 0.f;
  int col = lane & 1;
  for (int i = lo + (lane >> 1); i < hi; i += 32) s += z[i * 2 + col];
#pragma unroll
  for (int off = 32; off >= 2; off >>= 1) s += __shfl_down(s, off);
  if (lane < 2) {
    int n = hi - lo;
    out[g * 2 + lane] = s / (float)(n > 0 ? n : 1) + zc[lane];
  }
}

extern "C" void kernel_launch(void* const* d_in, const int* in_sizes, int n_in,
                              void* d_out, int out_size, void* d_ws, size_t ws_size,
                              hipStream_t stream) {
  const float* features = (const float*)d_in[0];
  const int* src = (const int*)d_in[1];
  const int* dst = (const int*)d_in[2];
  const int* gid = (const int*)d_in[3];
  const float* W1 = (const float*)d_in[4];
  const float* b1 = (const float*)d_in[5];
  const float* W2 = (const float*)d_in[6];
  const float* b2 = (const float*)d_in[7];
  const float* Wc = (const float*)d_in[8];
  const float* bc = (const float*)d_in[9];
  float* out = (float*)d_out;

  char* ws = (char*)d_ws;
  size_t off = 0;
  auto take = [&](size_t bytes) {
    char* p = ws + off;
    off = (off + bytes + 255) & ~(size_t)255;
    return p;
  };
  int* cur_d      = (int*)take(NSB * 4);
  int* cur_s      = (int*)take(NSB * 4);
  int* deg_in     = (int*)take((size_t)NN * 4);
  float* out_nrm  = (float*)take((size_t)NN * 4);
  float* in_nrm   = (float*)take((size_t)NN * 4);
  int* row_start  = (int*)take((size_t)NN * 4);
  float* pbuf     = (float*)take((size_t)NN * 2 * 4);
  float* zbuf     = (float*)take((size_t)NN * 2 * 4);
  float* w2c      = (float*)take((size_t)DD * 2 * 4);
  float* zc       = (float*)take(2 * 4);
  unsigned long long* byDst = (unsigned long long*)take((size_t)NSB * SBCAP * 8);
  unsigned short* bySrc = (unsigned short*)take((size_t)NSB * SBCAP * 2);
  int* csr        = (int*)take((size_t)NSB * SBCAP * 4);
  __half* xh      = (__half*)take((size_t)NN * DD * 2);
  float* bufA     = (float*)take((size_t)NN * DD * 4);
  _Float16* w1hi  = (_Float16*)take((size_t)DD * DD * 2);
  _Float16* w1lo  = (_Float16*)take((size_t)DD * DD * 2);

  hipMemsetAsync(cur_d, 0, NSB * 4, stream);
  hipMemsetAsync(cur_s, 0, NSB * 4, stream);

  k_wsplit<<<8, 256, 0, stream>>>(W1, w1hi, w1lo);
  k_w2c<<<1, 256, 0, stream>>>(W2, Wc, b2, bc, w2c, zc);
  k_bin<<<NB1, 256, 0, stream>>>(src, dst, cur_d, cur_s, byDst, bySrc);
  k_csr_dst<<<NSB, 1024, 0, stream>>>(byDst, cur_d, csr, row_start, deg_in);
  k_deg_src_norm<<<NSB, 1024, 0, stream>>>(bySrc, cur_s, deg_in, out_nrm, in_nrm);
  // f2h needs out_norm -> after norms
  k_f2h<<<(NN * 32 + 255) / 256, 256, 0, stream>>>(
      (const float4*)features, out_nrm, (uint2*)xh, NN * 32);

  // layer 1: agg(xh) -> bufA ; mfma-gemm+relu + fused 128->2 projection -> pbuf
  k_agg<<<(NN + 3) / 4, 256, 0, stream>>>(xh, csr, row_start, deg_in, bufA);
  k_gemm1<<<(NN + 63) / 64, 256, 0, stream>>>(
      bufA, in_nrm, out_nrm, w1hi, w1lo, b1, w2c, (float2*)pbuf);

  // layer 2 (algebraically reduced): 2-dim aggregate + norm -> zbuf
  k_agg2<<<(NN + 255) / 256, 256, 0, stream>>>(
      (const float2*)pbuf, csr, row_start, deg_in, in_nrm, (float2*)zbuf);

  // segment mean-pool (+ b2@Wc + bc)
  k_pool2<<<(NG + 3) / 4, 256, 0, stream>>>(zbuf, gid, zc, out);
}

// Round 15
// 136.022 us; speedup vs baseline: 2.2819x; 1.0253x over previous
//
#include <hip/hip_runtime.h>
#include <hip/hip_fp16.h>

#define NN 50000
#define NE 800000
#define NG 512
#define DD 128
#define NSB 64               // sub-bins == subpartitions
#define SUBN 782             // ceil(NN/NSB)
#define SBCAP 14336          // per-sub-bin capacity
#define NB1 512
#define NI4 (NE / 4)
#define CH4 ((NI4 + NB1 - 1) / NB1)

typedef __attribute__((ext_vector_type(8))) _Float16 f16x8;
typedef __attribute__((ext_vector_type(4))) float f32x4;
typedef int v4i __attribute__((ext_vector_type(4)));

// ---- P0: features f32 -> fp16, pre-scaled by out_norm (row-major) ----
__global__ __launch_bounds__(256) void k_f2h(
    const float4* __restrict__ in, const float* __restrict__ out_norm,
    uint2* __restrict__ out, int n4) {
  int i = blockIdx.x * 256 + threadIdx.x;
  if (i >= n4) return;                  // n4 = NN*32
  float w = out_norm[i >> 5];
  float4 v = in[i];
  __half2 a = __floats2half2_rn(v.x * w, v.y * w);
  __half2 b = __floats2half2_rn(v.z * w, v.w * w);
  uint2 o;
  o.x = *(unsigned int*)&a;
  o.y = *(unsigned int*)&b;
  out[i] = o;
}

// ---- merged prep: blocks 0-7 W1-split, block 8 W2c, blocks 9.. edge binning ----
__global__ __launch_bounds__(256) void k_prep(
    const float* __restrict__ W1, const float* __restrict__ W2,
    const float* __restrict__ Wc, const float* __restrict__ b2,
    const float* __restrict__ bc,
    _Float16* __restrict__ w1hi, _Float16* __restrict__ w1lo,
    float* __restrict__ w2c, float* __restrict__ zc,
    const int* __restrict__ src, const int* __restrict__ dst,
    int* __restrict__ cur_d, int* __restrict__ cur_s,
    unsigned long long* __restrict__ byDst, unsigned short* __restrict__ bySrc) {
  __shared__ int cntd[NSB], cnts[NSB], based[NSB], bases[NSB];
  int b = blockIdx.x;
  int tid = threadIdx.x;
  if (b < 8) {
    // W1 split into MFMA B-fragment order:
    // idx ((nt*4+kk)*64+lane)*8+j holds W[kk*32+(lane>>4)*8+j][nt*16+(lane&15)]
    int t = b * 256 + tid;
    int lane = t & 63;
    int grp = t >> 6;
    int kk = grp & 3;
    int nt = grp >> 2;
    int kbase = kk * 32 + ((lane >> 4) << 3);
    int c = nt * 16 + (lane & 15);
#pragma unroll
    for (int j = 0; j < 8; ++j) {
      float v = W1[(kbase + j) * DD + c];
      _Float16 h = (_Float16)v;
      w1hi[t * 8 + j] = h;
      w1lo[t * 8 + j] = (_Float16)(v - (float)h);
    }
  } else if (b == 8) {
    // W2c = W2 @ Wc [128][2]; zc = b2 @ Wc + bc [2]
    int row = tid >> 1, cc = tid & 1;
    float s = 0.f;
#pragma unroll 8
    for (int c = 0; c < DD; ++c) s += W2[row * DD + c] * Wc[c * 2 + cc];
    w2c[row * 2 + cc] = s;
    if (tid < 2) {
      float bb = 0.f;
      for (int c = 0; c < DD; ++c) bb += b2[c] * Wc[c * 2 + tid];
      zc[tid] = bb + bc[tid];
    }
  } else {
    // edge binning (chunk b-9): dst-keyed (d,s) u64; src-keyed u16 local id
    int i0 = (b - 9) * CH4;
    int i1 = i0 + CH4; if (i1 > NI4) i1 = NI4;
    if (tid < NSB) { cntd[tid] = 0; cnts[tid] = 0; }
    __syncthreads();
    const v4i* s4 = (const v4i*)src;
    const v4i* d4 = (const v4i*)dst;
    for (int i = i0 + tid; i < i1; i += 256) {
      v4i sv = __builtin_nontemporal_load(&s4[i]);
      v4i dv = __builtin_nontemporal_load(&d4[i]);
#pragma unroll
      for (int k = 0; k < 4; ++k) {
        atomicAdd(&cntd[dv[k] / SUBN], 1);
        atomicAdd(&cnts[sv[k] / SUBN], 1);
      }
    }
    __syncthreads();
    if (tid < NSB) {
      based[tid] = atomicAdd(&cur_d[tid], cntd[tid]);
      cntd[tid] = 0;
    } else if (tid < 2 * NSB) {
      int q = tid - NSB;
      bases[q] = atomicAdd(&cur_s[q], cnts[q]);
      cnts[q] = 0;
    }
    __syncthreads();
    for (int i = i0 + tid; i < i1; i += 256) {
      v4i sv = __builtin_nontemporal_load(&s4[i]);
      v4i dv = __builtin_nontemporal_load(&d4[i]);
#pragma unroll
      for (int k = 0; k < 4; ++k) {
        int d = dv[k], s = sv[k];
        int bd = d / SUBN;
        int pd = based[bd] + atomicAdd(&cntd[bd], 1);
        if (pd < SBCAP) byDst[(size_t)bd * SBCAP + pd] = ((unsigned long long)(unsigned)d << 32) | (unsigned)s;
        int bs = s / SUBN;
        int ps = bases[bs] + atomicAdd(&cnts[bs], 1);
        if (ps < SBCAP) bySrc[(size_t)bs * SBCAP + ps] = (unsigned short)(s - bs * SUBN);
      }
    }
  }
}

// ---- merged P2: blocks 0-63 dst-side (CSR + deg_in + in_norm),
//                 blocks 64-127 src-side (out_norm). No global atomics. ----
__global__ __launch_bounds__(1024) void k_csr2(
    const unsigned long long* __restrict__ byDst, const int* __restrict__ cur_d,
    const unsigned short* __restrict__ bySrc, const int* __restrict__ cur_s,
    int* __restrict__ csr, int* __restrict__ row_start, int* __restrict__ deg_in,
    float* __restrict__ in_norm, float* __restrict__ out_norm) {
  __shared__ int hist[SUBN];
  __shared__ int wsum[16];
  int b = blockIdx.x;
  int tid = threadIdx.x;
  if (b < 64) {
    int q = b;
    int nlo = q * SUBN;
    int nhi = nlo + SUBN; if (nhi > NN) nhi = NN;
    int nloc = nhi - nlo;
    for (int i = tid; i < SUBN; i += 1024) hist[i] = 0;
    __syncthreads();
    int m = cur_d[q];
    if (m > SBCAP) m = SBCAP;
    const unsigned long long* bine = byDst + (size_t)q * SBCAP;
    for (int i = tid; i < m; i += 1024) {
      int l = (int)(bine[i] >> 32) - nlo;
      if (l >= 0 && l < nloc) atomicAdd(&hist[l], 1);
    }
    __syncthreads();
    int v = (tid < SUBN) ? hist[tid] : 0;
    int incl = v;
    int lane = tid & 63;
#pragma unroll
    for (int off = 1; off < 64; off <<= 1) {
      int t2 = __shfl_up(incl, off);
      if (lane >= off) incl += t2;
    }
    int wid = tid >> 6;
    if (lane == 63) wsum[wid] = incl;
    __syncthreads();
    if (tid == 0) {
      int run = 0;
      for (int i = 0; i < 16; ++i) { int t = wsum[i]; wsum[i] = run; run += t; }
    }
    __syncthreads();
    int excl = incl - v + wsum[wid];
    if (tid < nloc) {
      deg_in[nlo + tid] = v;
      row_start[nlo + tid] = q * SBCAP + excl;
      in_norm[nlo + tid] = v > 0 ? rsqrtf((float)v) : 0.f;
    }
    __syncthreads();
    if (tid < SUBN) hist[tid] = excl;   // scatter cursor
    __syncthreads();
    for (int i = tid; i < m; i += 1024) {
      unsigned long long p = bine[i];
      int l = (int)(p >> 32) - nlo;
      if (l >= 0 && l < nloc) {
        int pos = atomicAdd(&hist[l], 1);
        if (pos < SBCAP) csr[(size_t)q * SBCAP + pos] = (int)(unsigned)p;
      }
    }
  } else {
    int q = b - 64;
    int nlo = q * SUBN;
    int nhi = nlo + SUBN; if (nhi > NN) nhi = NN;
    int nloc = nhi - nlo;
    for (int i = tid; i < SUBN; i += 1024) hist[i] = 0;
    __syncthreads();
    int m = cur_s[q];
    if (m > SBCAP) m = SBCAP;
    const unsigned short* bine = bySrc + (size_t)q * SBCAP;
    for (int i = tid; i < m; i += 1024) {
      atomicAdd(&hist[bine[i]], 1);
    }
    __syncthreads();
    for (int i = tid; i < nloc; i += 1024) {
      int od = hist[i];
      out_norm[nlo + i] = od > 0 ? rsqrtf((float)od) : 0.f;
    }
  }
}

// ---- fused: aggregation (LDS tile) + MFMA GEMM + layer-2 projection ----
// Phase 1: each wave aggregates its 16 rows (4-deep-MLP gather of pre-scaled
// fp16 rows) into As[64][132] (pad breaks bank aliasing).
// Phase 2: split-fp16 3-MFMA GEMM from LDS; epilogue computes
// p[row] = out_norm[row] * relu(in_norm*(A@W1)+b1) @ W2c  (2 floats).
__global__ __launch_bounds__(256, 4) void k_agg_gemm1(
    const __half* __restrict__ x, const int* __restrict__ csr,
    const int* __restrict__ row_start, const int* __restrict__ deg_in,
    const float* __restrict__ in_norm, const float* __restrict__ out_norm,
    const _Float16* __restrict__ Whi, const _Float16* __restrict__ Wlo,
    const float* __restrict__ bias, const float* __restrict__ W2c,
    float2* __restrict__ p) {
  __shared__ float As[64][132];
  int tid = threadIdx.x;
  int wid = tid >> 6, lane = tid & 63;
  int row0 = blockIdx.x * 64 + wid * 16;
  const __half2* xv = (const __half2*)x;

  // phase 1: aggregate 16 rows per wave
  for (int k = 0; k < 16; ++k) {
    int node = row0 + k;
    float2 a0 = {0.f, 0.f}, a1 = {0.f, 0.f}, a2 = {0.f, 0.f}, a3 = {0.f, 0.f};
    if (node < NN) {
      int n = deg_in[node];
      const int* bk = csr + row_start[node];
      for (int c0 = 0; c0 < n; c0 += 64) {
        int nn = n - c0; if (nn > 64) nn = 64;
        int sl = (lane < nn) ? bk[c0 + lane] : 0;
        int j = 0;
        for (; j + 4 <= nn; j += 4) {
          int s0 = __shfl(sl, j + 0), s1 = __shfl(sl, j + 1);
          int s2 = __shfl(sl, j + 2), s3 = __shfl(sl, j + 3);
          float2 v0 = __half22float2(xv[(size_t)s0 * 64 + lane]);
          float2 v1 = __half22float2(xv[(size_t)s1 * 64 + lane]);
          float2 v2 = __half22float2(xv[(size_t)s2 * 64 + lane]);
          float2 v3 = __half22float2(xv[(size_t)s3 * 64 + lane]);
          a0.x += v0.x; a0.y += v0.y;
          a1.x += v1.x; a1.y += v1.y;
          a2.x += v2.x; a2.y += v2.y;
          a3.x += v3.x; a3.y += v3.y;
        }
        for (; j < nn; ++j) {
          int s0 = __shfl(sl, j);
          float2 v0 = __half22float2(xv[(size_t)s0 * 64 + lane]);
          a0.x += v0.x; a0.y += v0.y;
        }
      }
      a0.x += a1.x + a2.x + a3.x;
      a0.y += a1.y + a2.y + a3.y;
    }
    *(float2*)&As[wid * 16 + k][lane * 2] = a0;
  }
  __syncthreads();

  // phase 2: MFMA GEMM from LDS
  int r = wid * 16 + (lane & 15);
  f16x8 ahi[4], alo[4];
#pragma unroll
  for (int kk = 0; kk < 4; ++kk) {
    int cb = kk * 32 + ((lane >> 4) << 3);
#pragma unroll
    for (int j = 0; j < 8; ++j) {
      float v = As[r][cb + j];
      _Float16 h = (_Float16)v;
      ahi[kk][j] = h;
      alo[kk][j] = (_Float16)(v - (float)h);
    }
  }
  f32x4 acc[8];
#pragma unroll
  for (int nt = 0; nt < 8; ++nt) acc[nt] = (f32x4){0.f, 0.f, 0.f, 0.f};
#pragma unroll
  for (int nt = 0; nt < 8; ++nt) {
#pragma unroll
    for (int kk = 0; kk < 4; ++kk) {
      f16x8 bh = *(const f16x8*)&Whi[(((nt * 4 + kk) * 64) + lane) * 8];
      f16x8 bl = *(const f16x8*)&Wlo[(((nt * 4 + kk) * 64) + lane) * 8];
      acc[nt] = __builtin_amdgcn_mfma_f32_16x16x32_f16(ahi[kk], bh, acc[nt], 0, 0, 0);
      acc[nt] = __builtin_amdgcn_mfma_f32_16x16x32_f16(ahi[kk], bl, acc[nt], 0, 0, 0);
      acc[nt] = __builtin_amdgcn_mfma_f32_16x16x32_f16(alo[kk], bh, acc[nt], 0, 0, 0);
    }
  }
  int r4 = (lane >> 4) * 4;
  int c0 = lane & 15;
  float wc0[8], wc1[8], bv[8];
#pragma unroll
  for (int nt = 0; nt < 8; ++nt) {
    int col = nt * 16 + c0;
    wc0[nt] = W2c[col * 2 + 0];
    wc1[nt] = W2c[col * 2 + 1];
    bv[nt] = bias[col];
  }
#pragma unroll
  for (int reg = 0; reg < 4; ++reg) {
    int row = row0 + r4 + reg;
    float inm = (row < NN) ? in_norm[row] : 0.f;
    float v0 = 0.f, v1 = 0.f;
#pragma unroll
    for (int nt = 0; nt < 8; ++nt) {
      float y = acc[nt][reg] * inm + bv[nt];
      y = fmaxf(y, 0.f);
      v0 += y * wc0[nt];
      v1 += y * wc1[nt];
    }
#pragma unroll
    for (int off = 1; off < 16; off <<= 1) {
      v0 += __shfl_xor(v0, off);
      v1 += __shfl_xor(v1, off);
    }
    if (row < NN && c0 == 0) {
      float onm = out_norm[row];
      p[row] = make_float2(v0 * onm, v1 * onm);
    }
  }
}

// ---- layer-2 aggregation on 2-dim projections: z[i] = in_norm[i] * sum p[nbr] ----
__global__ __launch_bounds__(256) void k_agg2(
    const float2* __restrict__ p, const int* __restrict__ csr,
    const int* __restrict__ row_start, const int* __restrict__ deg_in,
    const float* __restrict__ in_norm, float2* __restrict__ z) {
  int i = blockIdx.x * 256 + threadIdx.x;
  if (i >= NN) return;
  int n = deg_in[i];
  const int* bk = csr + row_start[i];
  float2 s0 = {0.f, 0.f}, s1 = {0.f, 0.f}, s2 = {0.f, 0.f}, s3 = {0.f, 0.f};
  int j = 0;
  for (; j + 4 <= n; j += 4) {
    int i0 = bk[j], i1 = bk[j + 1], i2 = bk[j + 2], i3 = bk[j + 3];
    float2 q0 = p[i0], q1 = p[i1], q2 = p[i2], q3 = p[i3];
    s0.x += q0.x; s0.y += q0.y;
    s1.x += q1.x; s1.y += q1.y;
    s2.x += q2.x; s2.y += q2.y;
    s3.x += q3.x; s3.y += q3.y;
  }
  for (; j < n; ++j) {
    float2 q = p[bk[j]];
    s0.x += q.x; s0.y += q.y;
  }
  s0.x += s1.x + s2.x + s3.x;
  s0.y += s1.y + s2.y + s3.y;
  float inm = in_norm[i];
  z[i] = make_float2(s0.x * inm, s0.y * inm);
}

// ---- pool: one wave per graph; segment-mean of z + zc -> out ----
__global__ __launch_bounds__(256) void k_pool2(
    const float* __restrict__ z, const int* __restrict__ gid,
    const float* __restrict__ zc, float* __restrict__ out) {
  int g = blockIdx.x * 4 + (threadIdx.x >> 6);
  int lane = threadIdx.x & 63;
  if (g >= NG) return;
  int lo, hi;
  { int a = 0, b = NN; while (a < b) { int m = (a + b) >> 1; if (gid[m] < g) a = m + 1; else b = m; } lo = a; }
  { int a = lo, b = NN; while (a < b) { int m = (a + b) >> 1; if (gid[m] <= g) a = m + 1; else b = m; } hi = a; }
  float s = 0.f;
  int col = lane & 1;
  for (int i = lo + (lane >> 1); i < hi; i += 32) s += z[i * 2 + col];
#pragma unroll
  for (int off = 32; off >= 2; off >>= 1) s += __shfl_down(s, off);
  if (lane < 2) {
    int n = hi - lo;
    out[g * 2 + lane] = s / (float)(n > 0 ? n : 1) + zc[lane];
  }
}

extern "C" void kernel_launch(void* const* d_in, const int* in_sizes, int n_in,
                              void* d_out, int out_size, void* d_ws, size_t ws_size,
                              hipStream_t stream) {
  const float* features = (const float*)d_in[0];
  const int* src = (const int*)d_in[1];
  const int* dst = (const int*)d_in[2];
  const int* gid = (const int*)d_in[3];
  const float* W1 = (const float*)d_in[4];
  const float* b1 = (const float*)d_in[5];
  const float* W2 = (const float*)d_in[6];
  const float* b2 = (const float*)d_in[7];
  const float* Wc = (const float*)d_in[8];
  const float* bc = (const float*)d_in[9];
  float* out = (float*)d_out;

  char* ws = (char*)d_ws;
  size_t off = 0;
  auto take = [&](size_t bytes) {
    char* p = ws + off;
    off = (off + bytes + 255) & ~(size_t)255;
    return p;
  };
  int* cur_d      = (int*)take(NSB * 4);
  int* cur_s      = (int*)take(NSB * 4);
  int* deg_in     = (int*)take((size_t)NN * 4);
  float* out_nrm  = (float*)take((size_t)NN * 4);
  float* in_nrm   = (float*)take((size_t)NN * 4);
  int* row_start  = (int*)take((size_t)NN * 4);
  float* pbuf     = (float*)take((size_t)NN * 2 * 4);
  float* zbuf     = (float*)take((size_t)NN * 2 * 4);
  float* w2c      = (float*)take((size_t)DD * 2 * 4);
  float* zc       = (float*)take(2 * 4);
  unsigned long long* byDst = (unsigned long long*)take((size_t)NSB * SBCAP * 8);
  unsigned short* bySrc = (unsigned short*)take((size_t)NSB * SBCAP * 2);
  int* csr        = (int*)take((size_t)NSB * SBCAP * 4);
  __half* xh      = (__half*)take((size_t)NN * DD * 2);
  _Float16* w1hi  = (_Float16*)take((size_t)DD * DD * 2);
  _Float16* w1lo  = (_Float16*)take((size_t)DD * DD * 2);

  hipMemsetAsync(cur_d, 0, NSB * 4, stream);
  hipMemsetAsync(cur_s, 0, NSB * 4, stream);

  // prep: W1 split (blocks 0-7) + W2c (block 8) + edge binning (blocks 9..520)
  k_prep<<<NB1 + 9, 256, 0, stream>>>(
      W1, W2, Wc, b2, bc, w1hi, w1lo, w2c, zc,
      src, dst, cur_d, cur_s, byDst, bySrc);

  // CSR build + degrees + norms (128 blocks: 64 dst-side, 64 src-side)
  k_csr2<<<128, 1024, 0, stream>>>(
      byDst, cur_d, bySrc, cur_s, csr, row_start, deg_in, in_nrm, out_nrm);

  // features -> fp16, pre-scaled by out_norm
  k_f2h<<<(NN * 32 + 255) / 256, 256, 0, stream>>>(
      (const float4*)features, out_nrm, (uint2*)xh, NN * 32);

  // fused layer 1: agg + MFMA GEMM + relu + 128->2 projection -> pbuf
  k_agg_gemm1<<<(NN + 63) / 64, 256, 0, stream>>>(
      xh, csr, row_start, deg_in, in_nrm, out_nrm, w1hi, w1lo, b1, w2c,
      (float2*)pbuf);

  // layer 2 (algebraically reduced): 2-dim aggregate + norm -> zbuf
  k_agg2<<<(NN + 255) / 256, 256, 0, stream>>>(
      (const float2*)pbuf, csr, row_start, deg_in, in_nrm, (float2*)zbuf);

  // segment mean-pool (+ b2@Wc + bc)
  k_pool2<<<(NG + 3) / 4, 256, 0, stream>>>(zbuf, gid, zc, out);
}

// Round 16
// 124.000 us; speedup vs baseline: 2.5031x; 1.0970x over previous
//
#include <hip/hip_runtime.h>
#include <hip/hip_fp16.h>

#define NN 50000
#define NE 800000
#define NG 512
#define DD 128
#define NSB 64               // sub-bins == subpartitions
#define SUBN 782             // ceil(NN/NSB)
#define SBCAP 14336          // per-sub-bin capacity
#define NB1 512
#define NI4 (NE / 4)
#define CH4 ((NI4 + NB1 - 1) / NB1)

typedef __attribute__((ext_vector_type(8))) _Float16 f16x8;
typedef __attribute__((ext_vector_type(4))) float f32x4;
typedef int v4i __attribute__((ext_vector_type(4)));

// ---- P0: features f32 -> fp16, pre-scaled by out_norm (row-major) ----
__global__ __launch_bounds__(256) void k_f2h(
    const float4* __restrict__ in, const float* __restrict__ out_norm,
    uint2* __restrict__ out, int n4) {
  int i = blockIdx.x * 256 + threadIdx.x;
  if (i >= n4) return;                  // n4 = NN*32
  float w = out_norm[i >> 5];
  float4 v = in[i];
  __half2 a = __floats2half2_rn(v.x * w, v.y * w);
  __half2 b = __floats2half2_rn(v.z * w, v.w * w);
  uint2 o;
  o.x = *(unsigned int*)&a;
  o.y = *(unsigned int*)&b;
  out[i] = o;
}

// ---- merged prep: blocks 0-7 W1-split, block 8 W2c, blocks 9.. edge binning ----
__global__ __launch_bounds__(256) void k_prep(
    const float* __restrict__ W1, const float* __restrict__ W2,
    const float* __restrict__ Wc, const float* __restrict__ b2,
    const float* __restrict__ bc,
    _Float16* __restrict__ w1hi, _Float16* __restrict__ w1lo,
    float* __restrict__ w2c, float* __restrict__ zc,
    const int* __restrict__ src, const int* __restrict__ dst,
    int* __restrict__ cur_d, int* __restrict__ cur_s,
    unsigned long long* __restrict__ byDst, unsigned short* __restrict__ bySrc) {
  __shared__ int cntd[NSB], cnts[NSB], based[NSB], bases[NSB];
  int b = blockIdx.x;
  int tid = threadIdx.x;
  if (b < 8) {
    // W1 split into MFMA B-fragment order:
    // idx ((nt*4+kk)*64+lane)*8+j holds W[kk*32+(lane>>4)*8+j][nt*16+(lane&15)]
    int t = b * 256 + tid;
    int lane = t & 63;
    int grp = t >> 6;
    int kk = grp & 3;
    int nt = grp >> 2;
    int kbase = kk * 32 + ((lane >> 4) << 3);
    int c = nt * 16 + (lane & 15);
#pragma unroll
    for (int j = 0; j < 8; ++j) {
      float v = W1[(kbase + j) * DD + c];
      _Float16 h = (_Float16)v;
      w1hi[t * 8 + j] = h;
      w1lo[t * 8 + j] = (_Float16)(v - (float)h);
    }
  } else if (b == 8) {
    // W2c = W2 @ Wc [128][2]; zc = b2 @ Wc + bc [2]
    int row = tid >> 1, cc = tid & 1;
    float s = 0.f;
#pragma unroll 8
    for (int c = 0; c < DD; ++c) s += W2[row * DD + c] * Wc[c * 2 + cc];
    w2c[row * 2 + cc] = s;
    if (tid < 2) {
      float bb = 0.f;
      for (int c = 0; c < DD; ++c) bb += b2[c] * Wc[c * 2 + tid];
      zc[tid] = bb + bc[tid];
    }
  } else {
    // edge binning (chunk b-9): dst-keyed (d,s) u64; src-keyed u16 local id
    int i0 = (b - 9) * CH4;
    int i1 = i0 + CH4; if (i1 > NI4) i1 = NI4;
    if (tid < NSB) { cntd[tid] = 0; cnts[tid] = 0; }
    __syncthreads();
    const v4i* s4 = (const v4i*)src;
    const v4i* d4 = (const v4i*)dst;
    for (int i = i0 + tid; i < i1; i += 256) {
      v4i sv = __builtin_nontemporal_load(&s4[i]);
      v4i dv = __builtin_nontemporal_load(&d4[i]);
#pragma unroll
      for (int k = 0; k < 4; ++k) {
        atomicAdd(&cntd[dv[k] / SUBN], 1);
        atomicAdd(&cnts[sv[k] / SUBN], 1);
      }
    }
    __syncthreads();
    if (tid < NSB) {
      based[tid] = atomicAdd(&cur_d[tid], cntd[tid]);
      cntd[tid] = 0;
    } else if (tid < 2 * NSB) {
      int q = tid - NSB;
      bases[q] = atomicAdd(&cur_s[q], cnts[q]);
      cnts[q] = 0;
    }
    __syncthreads();
    for (int i = i0 + tid; i < i1; i += 256) {
      v4i sv = __builtin_nontemporal_load(&s4[i]);
      v4i dv = __builtin_nontemporal_load(&d4[i]);
#pragma unroll
      for (int k = 0; k < 4; ++k) {
        int d = dv[k], s = sv[k];
        int bd = d / SUBN;
        int pd = based[bd] + atomicAdd(&cntd[bd], 1);
        if (pd < SBCAP) byDst[(size_t)bd * SBCAP + pd] = ((unsigned long long)(unsigned)d << 32) | (unsigned)s;
        int bs = s / SUBN;
        int ps = bases[bs] + atomicAdd(&cnts[bs], 1);
        if (ps < SBCAP) bySrc[(size_t)bs * SBCAP + ps] = (unsigned short)(s - bs * SUBN);
      }
    }
  }
}

// ---- merged P2: blocks 0-63 dst-side (CSR + deg_in + in_norm),
//                 blocks 64-127 src-side (out_norm). No global atomics. ----
__global__ __launch_bounds__(1024) void k_csr2(
    const unsigned long long* __restrict__ byDst, const int* __restrict__ cur_d,
    const unsigned short* __restrict__ bySrc, const int* __restrict__ cur_s,
    int* __restrict__ csr, int* __restrict__ row_start, int* __restrict__ deg_in,
    float* __restrict__ in_norm, float* __restrict__ out_norm) {
  __shared__ int hist[SUBN];
  __shared__ int wsum[16];
  int b = blockIdx.x;
  int tid = threadIdx.x;
  if (b < 64) {
    int q = b;
    int nlo = q * SUBN;
    int nhi = nlo + SUBN; if (nhi > NN) nhi = NN;
    int nloc = nhi - nlo;
    for (int i = tid; i < SUBN; i += 1024) hist[i] = 0;
    __syncthreads();
    int m = cur_d[q];
    if (m > SBCAP) m = SBCAP;
    const unsigned long long* bine = byDst + (size_t)q * SBCAP;
    for (int i = tid; i < m; i += 1024) {
      int l = (int)(bine[i] >> 32) - nlo;
      if (l >= 0 && l < nloc) atomicAdd(&hist[l], 1);
    }
    __syncthreads();
    int v = (tid < SUBN) ? hist[tid] : 0;
    int incl = v;
    int lane = tid & 63;
#pragma unroll
    for (int off = 1; off < 64; off <<= 1) {
      int t2 = __shfl_up(incl, off);
      if (lane >= off) incl += t2;
    }
    int wid = tid >> 6;
    if (lane == 63) wsum[wid] = incl;
    __syncthreads();
    if (tid == 0) {
      int run = 0;
      for (int i = 0; i < 16; ++i) { int t = wsum[i]; wsum[i] = run; run += t; }
    }
    __syncthreads();
    int excl = incl - v + wsum[wid];
    if (tid < nloc) {
      deg_in[nlo + tid] = v;
      row_start[nlo + tid] = q * SBCAP + excl;
      in_norm[nlo + tid] = v > 0 ? rsqrtf((float)v) : 0.f;
    }
    __syncthreads();
    if (tid < SUBN) hist[tid] = excl;   // scatter cursor
    __syncthreads();
    for (int i = tid; i < m; i += 1024) {
      unsigned long long p = bine[i];
      int l = (int)(p >> 32) - nlo;
      if (l >= 0 && l < nloc) {
        int pos = atomicAdd(&hist[l], 1);
        if (pos < SBCAP) csr[(size_t)q * SBCAP + pos] = (int)(unsigned)p;
      }
    }
  } else {
    int q = b - 64;
    int nlo = q * SUBN;
    int nhi = nlo + SUBN; if (nhi > NN) nhi = NN;
    int nloc = nhi - nlo;
    for (int i = tid; i < SUBN; i += 1024) hist[i] = 0;
    __syncthreads();
    int m = cur_s[q];
    if (m > SBCAP) m = SBCAP;
    const unsigned short* bine = bySrc + (size_t)q * SBCAP;
    for (int i = tid; i < m; i += 1024) {
      atomicAdd(&hist[bine[i]], 1);
    }
    __syncthreads();
    for (int i = tid; i < nloc; i += 1024) {
      int od = hist[i];
      out_norm[nlo + i] = od > 0 ? rsqrtf((float)od) : 0.f;
    }
  }
}

// ---- aggregation (layer 1): one wave per dst node, fp16 pre-scaled gather,
// f32 accumulate, 8-deep MLP (latency-bound -> maximize loads in flight). ----
__global__ __launch_bounds__(256) void k_agg(
    const __half* __restrict__ x, const int* __restrict__ csr,
    const int* __restrict__ row_start, const int* __restrict__ deg_in,
    float* __restrict__ agg) {
  int node = blockIdx.x * 4 + (threadIdx.x >> 6);
  int lane = threadIdx.x & 63;
  if (node >= NN) return;
  int n = deg_in[node];
  const int* bk = csr + row_start[node];
  const __half2* xv = (const __half2*)x;
  float2 a0 = {0.f, 0.f}, a1 = {0.f, 0.f}, a2 = {0.f, 0.f}, a3 = {0.f, 0.f};
  float2 a4 = {0.f, 0.f}, a5 = {0.f, 0.f}, a6 = {0.f, 0.f}, a7 = {0.f, 0.f};
  for (int c0 = 0; c0 < n; c0 += 64) {
    int nn = n - c0; if (nn > 64) nn = 64;
    int sl = (lane < nn) ? bk[c0 + lane] : 0;
    int j = 0;
    for (; j + 8 <= nn; j += 8) {
      int s0 = __shfl(sl, j + 0), s1 = __shfl(sl, j + 1);
      int s2 = __shfl(sl, j + 2), s3 = __shfl(sl, j + 3);
      int s4 = __shfl(sl, j + 4), s5 = __shfl(sl, j + 5);
      int s6 = __shfl(sl, j + 6), s7 = __shfl(sl, j + 7);
      float2 v0 = __half22float2(xv[(size_t)s0 * 64 + lane]);
      float2 v1 = __half22float2(xv[(size_t)s1 * 64 + lane]);
      float2 v2 = __half22float2(xv[(size_t)s2 * 64 + lane]);
      float2 v3 = __half22float2(xv[(size_t)s3 * 64 + lane]);
      float2 v4 = __half22float2(xv[(size_t)s4 * 64 + lane]);
      float2 v5 = __half22float2(xv[(size_t)s5 * 64 + lane]);
      float2 v6 = __half22float2(xv[(size_t)s6 * 64 + lane]);
      float2 v7 = __half22float2(xv[(size_t)s7 * 64 + lane]);
      a0.x += v0.x; a0.y += v0.y;
      a1.x += v1.x; a1.y += v1.y;
      a2.x += v2.x; a2.y += v2.y;
      a3.x += v3.x; a3.y += v3.y;
      a4.x += v4.x; a4.y += v4.y;
      a5.x += v5.x; a5.y += v5.y;
      a6.x += v6.x; a6.y += v6.y;
      a7.x += v7.x; a7.y += v7.y;
    }
    for (; j + 4 <= nn; j += 4) {
      int s0 = __shfl(sl, j + 0), s1 = __shfl(sl, j + 1);
      int s2 = __shfl(sl, j + 2), s3 = __shfl(sl, j + 3);
      float2 v0 = __half22float2(xv[(size_t)s0 * 64 + lane]);
      float2 v1 = __half22float2(xv[(size_t)s1 * 64 + lane]);
      float2 v2 = __half22float2(xv[(size_t)s2 * 64 + lane]);
      float2 v3 = __half22float2(xv[(size_t)s3 * 64 + lane]);
      a0.x += v0.x; a0.y += v0.y;
      a1.x += v1.x; a1.y += v1.y;
      a2.x += v2.x; a2.y += v2.y;
      a3.x += v3.x; a3.y += v3.y;
    }
    for (; j < nn; ++j) {
      int s0 = __shfl(sl, j);
      float2 v0 = __half22float2(xv[(size_t)s0 * 64 + lane]);
      a0.x += v0.x; a0.y += v0.y;
    }
  }
  a0.x += a1.x + a2.x + a3.x + a4.x + a5.x + a6.x + a7.x;
  a0.y += a1.y + a2.y + a3.y + a4.y + a5.y + a6.y + a7.y;
  ((float2*)agg)[(size_t)node * 64 + lane] = a0;
}

// ---- layer-1 MFMA GEMM + fused layer-2 projection ----
// h1 = relu(in_norm*(A@W1) + b1)   (in registers only, never stored)
// p[row] = out_norm[row] * (h1 @ W2c)   [2 floats per row]
__global__ __launch_bounds__(256, 4) void k_gemm1(
    const float* __restrict__ A, const float* __restrict__ in_norm,
    const float* __restrict__ out_norm,
    const _Float16* __restrict__ Whi, const _Float16* __restrict__ Wlo,
    const float* __restrict__ bias, const float* __restrict__ W2c,
    float2* __restrict__ p) {
  int tid = threadIdx.x;
  int wid = tid >> 6, lane = tid & 63;
  int row0 = blockIdx.x * 64 + wid * 16;
  int ar = row0 + (lane & 15);
  bool rv = ar < NN;
  f16x8 ahi[4], alo[4];
#pragma unroll
  for (int kk = 0; kk < 4; ++kk) {
    f32x4 u0 = {0.f, 0.f, 0.f, 0.f}, u1 = {0.f, 0.f, 0.f, 0.f};
    if (rv) {
      const f32x4* ap = (const f32x4*)(A + (size_t)ar * DD + kk * 32 + ((lane >> 4) << 3));
      u0 = __builtin_nontemporal_load(ap);
      u1 = __builtin_nontemporal_load(ap + 1);
    }
    float v[8] = {u0.x, u0.y, u0.z, u0.w, u1.x, u1.y, u1.z, u1.w};
#pragma unroll
    for (int j = 0; j < 8; ++j) {
      _Float16 h = (_Float16)v[j];
      ahi[kk][j] = h;
      alo[kk][j] = (_Float16)(v[j] - (float)h);
    }
  }
  f32x4 acc[8];
#pragma unroll
  for (int nt = 0; nt < 8; ++nt) acc[nt] = (f32x4){0.f, 0.f, 0.f, 0.f};
#pragma unroll
  for (int nt = 0; nt < 8; ++nt) {
#pragma unroll
    for (int kk = 0; kk < 4; ++kk) {
      f16x8 bh = *(const f16x8*)&Whi[(((nt * 4 + kk) * 64) + lane) * 8];
      f16x8 bl = *(const f16x8*)&Wlo[(((nt * 4 + kk) * 64) + lane) * 8];
      acc[nt] = __builtin_amdgcn_mfma_f32_16x16x32_f16(ahi[kk], bh, acc[nt], 0, 0, 0);
      acc[nt] = __builtin_amdgcn_mfma_f32_16x16x32_f16(ahi[kk], bl, acc[nt], 0, 0, 0);
      acc[nt] = __builtin_amdgcn_mfma_f32_16x16x32_f16(alo[kk], bh, acc[nt], 0, 0, 0);
    }
  }
  int r4 = (lane >> 4) * 4;
  int c0 = lane & 15;
  float wc0[8], wc1[8], bv[8];
#pragma unroll
  for (int nt = 0; nt < 8; ++nt) {
    int col = nt * 16 + c0;
    wc0[nt] = W2c[col * 2 + 0];
    wc1[nt] = W2c[col * 2 + 1];
    bv[nt] = bias[col];
  }
#pragma unroll
  for (int reg = 0; reg < 4; ++reg) {
    int row = row0 + r4 + reg;
    float inm = (row < NN) ? in_norm[row] : 0.f;
    float v0 = 0.f, v1 = 0.f;
#pragma unroll
    for (int nt = 0; nt < 8; ++nt) {
      float y = acc[nt][reg] * inm + bv[nt];
      y = fmaxf(y, 0.f);
      v0 += y * wc0[nt];
      v1 += y * wc1[nt];
    }
#pragma unroll
    for (int off = 1; off < 16; off <<= 1) {
      v0 += __shfl_xor(v0, off);
      v1 += __shfl_xor(v1, off);
    }
    if (row < NN && c0 == 0) {
      float onm = out_norm[row];
      p[row] = make_float2(v0 * onm, v1 * onm);
    }
  }
}

// ---- layer-2 aggregation on 2-dim projections: z[i] = in_norm[i] * sum p[nbr] ----
__global__ __launch_bounds__(256) void k_agg2(
    const float2* __restrict__ p, const int* __restrict__ csr,
    const int* __restrict__ row_start, const int* __restrict__ deg_in,
    const float* __restrict__ in_norm, float2* __restrict__ z) {
  int i = blockIdx.x * 256 + threadIdx.x;
  if (i >= NN) return;
  int n = deg_in[i];
  const int* bk = csr + row_start[i];
  float2 s0 = {0.f, 0.f}, s1 = {0.f, 0.f}, s2 = {0.f, 0.f}, s3 = {0.f, 0.f};
  int j = 0;
  for (; j + 4 <= n; j += 4) {
    int i0 = bk[j], i1 = bk[j + 1], i2 = bk[j + 2], i3 = bk[j + 3];
    float2 q0 = p[i0], q1 = p[i1], q2 = p[i2], q3 = p[i3];
    s0.x += q0.x; s0.y += q0.y;
    s1.x += q1.x; s1.y += q1.y;
    s2.x += q2.x; s2.y += q2.y;
    s3.x += q3.x; s3.y += q3.y;
  }
  for (; j < n; ++j) {
    float2 q = p[bk[j]];
    s0.x += q.x; s0.y += q.y;
  }
  s0.x += s1.x + s2.x + s3.x;
  s0.y += s1.y + s2.y + s3.y;
  float inm = in_norm[i];
  z[i] = make_float2(s0.x * inm, s0.y * inm);
}

// ---- pool: one wave per graph; segment-mean of z + zc -> out ----
__global__ __launch_bounds__(256) void k_pool2(
    const float* __restrict__ z, const int* __restrict__ gid,
    const float* __restrict__ zc, float* __restrict__ out) {
  int g = blockIdx.x * 4 + (threadIdx.x >> 6);
  int lane = threadIdx.x & 63;
  if (g >= NG) return;
  int lo, hi;
  { int a = 0, b = NN; while (a < b) { int m = (a + b) >> 1; if (gid[m] < g) a = m + 1; else b = m; } lo = a; }
  { int a = lo, b = NN; while (a < b) { int m = (a + b) >> 1; if (gid[m] <= g) a = m + 1; else b = m; } hi = a; }
  float s = 0.f;
  int col = lane & 1;
  for (int i = lo + (lane >> 1); i < hi; i += 32) s += z[i * 2 + col];
#pragma unroll
  for (int off = 32; off >= 2; off >>= 1) s += __shfl_down(s, off);
  if (lane < 2) {
    int n = hi - lo;
    out[g * 2 + lane] = s / (float)(n > 0 ? n : 1) + zc[lane];
  }
}

extern "C" void kernel_launch(void* const* d_in, const int* in_sizes, int n_in,
                              void* d_out, int out_size, void* d_ws, size_t ws_size,
                              hipStream_t stream) {
  const float* features = (const float*)d_in[0];
  const int* src = (const int*)d_in[1];
  const int* dst = (const int*)d_in[2];
  const int* gid = (const int*)d_in[3];
  const float* W1 = (const float*)d_in[4];
  const float* b1 = (const float*)d_in[5];
  const float* W2 = (const float*)d_in[6];
  const float* b2 = (const float*)d_in[7];
  const float* Wc = (const float*)d_in[8];
  const float* bc = (const float*)d_in[9];
  float* out = (float*)d_out;

  char* ws = (char*)d_ws;
  size_t off = 0;
  auto take = [&](size_t bytes) {
    char* p = ws + off;
    off = (off + bytes + 255) & ~(size_t)255;
    return p;
  };
  int* cur_d      = (int*)take(NSB * 4);
  int* cur_s      = (int*)take(NSB * 4);
  int* deg_in     = (int*)take((size_t)NN * 4);
  float* out_nrm  = (float*)take((size_t)NN * 4);
  float* in_nrm   = (float*)take((size_t)NN * 4);
  int* row_start  = (int*)take((size_t)NN * 4);
  float* pbuf     = (float*)take((size_t)NN * 2 * 4);
  float* zbuf     = (float*)take((size_t)NN * 2 * 4);
  float* w2c      = (float*)take((size_t)DD * 2 * 4);
  float* zc       = (float*)take(2 * 4);
  unsigned long long* byDst = (unsigned long long*)take((size_t)NSB * SBCAP * 8);
  unsigned short* bySrc = (unsigned short*)take((size_t)NSB * SBCAP * 2);
  int* csr        = (int*)take((size_t)NSB * SBCAP * 4);
  __half* xh      = (__half*)take((size_t)NN * DD * 2);
  float* bufA     = (float*)take((size_t)NN * DD * 4);
  _Float16* w1hi  = (_Float16*)take((size_t)DD * DD * 2);
  _Float16* w1lo  = (_Float16*)take((size_t)DD * DD * 2);

  hipMemsetAsync(cur_d, 0, NSB * 4, stream);
  hipMemsetAsync(cur_s, 0, NSB * 4, stream);

  // prep: W1 split (blocks 0-7) + W2c (block 8) + edge binning (blocks 9..520)
  k_prep<<<NB1 + 9, 256, 0, stream>>>(
      W1, W2, Wc, b2, bc, w1hi, w1lo, w2c, zc,
      src, dst, cur_d, cur_s, byDst, bySrc);

  // CSR build + degrees + norms (128 blocks: 64 dst-side, 64 src-side)
  k_csr2<<<128, 1024, 0, stream>>>(
      byDst, cur_d, bySrc, cur_s, csr, row_start, deg_in, in_nrm, out_nrm);

  // features -> fp16, pre-scaled by out_norm
  k_f2h<<<(NN * 32 + 255) / 256, 256, 0, stream>>>(
      (const float4*)features, out_nrm, (uint2*)xh, NN * 32);

  // layer 1: agg (high-occupancy, 8-deep) -> bufA ; MFMA GEMM + projection -> pbuf
  k_agg<<<(NN + 3) / 4, 256, 0, stream>>>(xh, csr, row_start, deg_in, bufA);
  k_gemm1<<<(NN + 63) / 64, 256, 0, stream>>>(
      bufA, in_nrm, out_nrm, w1hi, w1lo, b1, w2c, (float2*)pbuf);

  // layer 2 (algebraically reduced): 2-dim aggregate + norm -> zbuf
  k_agg2<<<(NN + 255) / 256, 256, 0, stream>>>(
      (const float2*)pbuf, csr, row_start, deg_in, in_nrm, (float2*)zbuf);

  // segment mean-pool (+ b2@Wc + bc)
  k_pool2<<<(NG + 3) / 4, 256, 0, stream>>>(zbuf, gid, zc, out);
}

// Round 17
// 117.783 us; speedup vs baseline: 2.6353x; 1.0528x over previous
//
#include <hip/hip_runtime.h>
#include <hip/hip_fp16.h>

#define NN 50000
#define NE 800000
#define NG 512
#define DD 128
#define NSB 64               // sub-bins == subpartitions
#define SUBN 782             // ceil(NN/NSB)
#define SBCAP 14336          // per-sub-bin capacity
#define NB1 512
#define NI4 (NE / 4)
#define CH4 ((NI4 + NB1 - 1) / NB1)

typedef __attribute__((ext_vector_type(8))) _Float16 f16x8;
typedef __attribute__((ext_vector_type(4))) float f32x4;
typedef int v4i __attribute__((ext_vector_type(4)));

// ---- P0: features f32 -> fp16, pre-scaled by out_norm (row-major) ----
__global__ __launch_bounds__(256) void k_f2h(
    const float4* __restrict__ in, const float* __restrict__ out_norm,
    uint2* __restrict__ out, int n4) {
  int i = blockIdx.x * 256 + threadIdx.x;
  if (i >= n4) return;                  // n4 = NN*32
  float w = out_norm[i >> 5];
  float4 v = in[i];
  __half2 a = __floats2half2_rn(v.x * w, v.y * w);
  __half2 b = __floats2half2_rn(v.z * w, v.w * w);
  uint2 o;
  o.x = *(unsigned int*)&a;
  o.y = *(unsigned int*)&b;
  out[i] = o;
}

// ---- merged prep: blocks 0-7 W1-split, block 8 W2c, blocks 9.. edge binning ----
__global__ __launch_bounds__(256) void k_prep(
    const float* __restrict__ W1, const float* __restrict__ W2,
    const float* __restrict__ Wc, const float* __restrict__ b2,
    const float* __restrict__ bc,
    _Float16* __restrict__ w1hi, _Float16* __restrict__ w1lo,
    float* __restrict__ w2c, float* __restrict__ zc,
    const int* __restrict__ src, const int* __restrict__ dst,
    int* __restrict__ cur_d, int* __restrict__ cur_s,
    unsigned long long* __restrict__ byDst, unsigned short* __restrict__ bySrc) {
  __shared__ int cntd[NSB], cnts[NSB], based[NSB], bases[NSB];
  int b = blockIdx.x;
  int tid = threadIdx.x;
  if (b < 8) {
    // W1 split into MFMA B-fragment order:
    // idx ((nt*4+kk)*64+lane)*8+j holds W[kk*32+(lane>>4)*8+j][nt*16+(lane&15)]
    int t = b * 256 + tid;
    int lane = t & 63;
    int grp = t >> 6;
    int kk = grp & 3;
    int nt = grp >> 2;
    int kbase = kk * 32 + ((lane >> 4) << 3);
    int c = nt * 16 + (lane & 15);
#pragma unroll
    for (int j = 0; j < 8; ++j) {
      float v = W1[(kbase + j) * DD + c];
      _Float16 h = (_Float16)v;
      w1hi[t * 8 + j] = h;
      w1lo[t * 8 + j] = (_Float16)(v - (float)h);
    }
  } else if (b == 8) {
    // W2c = W2 @ Wc [128][2]; zc = b2 @ Wc + bc [2]
    int row = tid >> 1, cc = tid & 1;
    float s = 0.f;
#pragma unroll 8
    for (int c = 0; c < DD; ++c) s += W2[row * DD + c] * Wc[c * 2 + cc];
    w2c[row * 2 + cc] = s;
    if (tid < 2) {
      float bb = 0.f;
      for (int c = 0; c < DD; ++c) bb += b2[c] * Wc[c * 2 + tid];
      zc[tid] = bb + bc[tid];
    }
  } else {
    // edge binning (chunk b-9): dst-keyed (d,s) u64; src-keyed u16 local id
    int i0 = (b - 9) * CH4;
    int i1 = i0 + CH4; if (i1 > NI4) i1 = NI4;
    if (tid < NSB) { cntd[tid] = 0; cnts[tid] = 0; }
    __syncthreads();
    const v4i* s4 = (const v4i*)src;
    const v4i* d4 = (const v4i*)dst;
    for (int i = i0 + tid; i < i1; i += 256) {
      v4i sv = __builtin_nontemporal_load(&s4[i]);
      v4i dv = __builtin_nontemporal_load(&d4[i]);
#pragma unroll
      for (int k = 0; k < 4; ++k) {
        atomicAdd(&cntd[dv[k] / SUBN], 1);
        atomicAdd(&cnts[sv[k] / SUBN], 1);
      }
    }
    __syncthreads();
    if (tid < NSB) {
      based[tid] = atomicAdd(&cur_d[tid], cntd[tid]);
      cntd[tid] = 0;
    } else if (tid < 2 * NSB) {
      int q = tid - NSB;
      bases[q] = atomicAdd(&cur_s[q], cnts[q]);
      cnts[q] = 0;
    }
    __syncthreads();
    for (int i = i0 + tid; i < i1; i += 256) {
      v4i sv = __builtin_nontemporal_load(&s4[i]);
      v4i dv = __builtin_nontemporal_load(&d4[i]);
#pragma unroll
      for (int k = 0; k < 4; ++k) {
        int d = dv[k], s = sv[k];
        int bd = d / SUBN;
        int pd = based[bd] + atomicAdd(&cntd[bd], 1);
        if (pd < SBCAP) byDst[(size_t)bd * SBCAP + pd] = ((unsigned long long)(unsigned)d << 32) | (unsigned)s;
        int bs = s / SUBN;
        int ps = bases[bs] + atomicAdd(&cnts[bs], 1);
        if (ps < SBCAP) bySrc[(size_t)bs * SBCAP + ps] = (unsigned short)(s - bs * SUBN);
      }
    }
  }
}

// ---- merged P2: blocks 0-63 dst-side (CSR + deg_in + in_norm),
//                 blocks 64-127 src-side (out_norm). No global atomics. ----
__global__ __launch_bounds__(1024) void k_csr2(
    const unsigned long long* __restrict__ byDst, const int* __restrict__ cur_d,
    const unsigned short* __restrict__ bySrc, const int* __restrict__ cur_s,
    int* __restrict__ csr, int* __restrict__ row_start, int* __restrict__ deg_in,
    float* __restrict__ in_norm, float* __restrict__ out_norm) {
  __shared__ int hist[SUBN];
  __shared__ int wsum[16];
  int b = blockIdx.x;
  int tid = threadIdx.x;
  if (b < 64) {
    int q = b;
    int nlo = q * SUBN;
    int nhi = nlo + SUBN; if (nhi > NN) nhi = NN;
    int nloc = nhi - nlo;
    for (int i = tid; i < SUBN; i += 1024) hist[i] = 0;
    __syncthreads();
    int m = cur_d[q];
    if (m > SBCAP) m = SBCAP;
    const unsigned long long* bine = byDst + (size_t)q * SBCAP;
    for (int i = tid; i < m; i += 1024) {
      int l = (int)(bine[i] >> 32) - nlo;
      if (l >= 0 && l < nloc) atomicAdd(&hist[l], 1);
    }
    __syncthreads();
    int v = (tid < SUBN) ? hist[tid] : 0;
    int incl = v;
    int lane = tid & 63;
#pragma unroll
    for (int off = 1; off < 64; off <<= 1) {
      int t2 = __shfl_up(incl, off);
      if (lane >= off) incl += t2;
    }
    int wid = tid >> 6;
    if (lane == 63) wsum[wid] = incl;
    __syncthreads();
    if (tid == 0) {
      int run = 0;
      for (int i = 0; i < 16; ++i) { int t = wsum[i]; wsum[i] = run; run += t; }
    }
    __syncthreads();
    int excl = incl - v + wsum[wid];
    if (tid < nloc) {
      deg_in[nlo + tid] = v;
      row_start[nlo + tid] = q * SBCAP + excl;
      in_norm[nlo + tid] = v > 0 ? rsqrtf((float)v) : 0.f;
    }
    __syncthreads();
    if (tid < SUBN) hist[tid] = excl;   // scatter cursor
    __syncthreads();
    for (int i = tid; i < m; i += 1024) {
      unsigned long long p = bine[i];
      int l = (int)(p >> 32) - nlo;
      if (l >= 0 && l < nloc) {
        int pos = atomicAdd(&hist[l], 1);
        if (pos < SBCAP) csr[(size_t)q * SBCAP + pos] = (int)(unsigned)p;
      }
    }
  } else {
    int q = b - 64;
    int nlo = q * SUBN;
    int nhi = nlo + SUBN; if (nhi > NN) nhi = NN;
    int nloc = nhi - nlo;
    for (int i = tid; i < SUBN; i += 1024) hist[i] = 0;
    __syncthreads();
    int m = cur_s[q];
    if (m > SBCAP) m = SBCAP;
    const unsigned short* bine = bySrc + (size_t)q * SBCAP;
    for (int i = tid; i < m; i += 1024) {
      atomicAdd(&hist[bine[i]], 1);
    }
    __syncthreads();
    for (int i = tid; i < nloc; i += 1024) {
      int od = hist[i];
      out_norm[nlo + i] = od > 0 ? rsqrtf((float)od) : 0.f;
    }
  }
}

// ---- aggregation (layer 1): one wave per dst node, fp16 pre-scaled gather,
// f32 accumulate, 8-deep MLP; OUTPUT fp16 (halves bufA traffic). ----
__global__ __launch_bounds__(256) void k_agg(
    const __half* __restrict__ x, const int* __restrict__ csr,
    const int* __restrict__ row_start, const int* __restrict__ deg_in,
    __half2* __restrict__ agg) {
  int node = blockIdx.x * 4 + (threadIdx.x >> 6);
  int lane = threadIdx.x & 63;
  if (node >= NN) return;
  int n = deg_in[node];
  const int* bk = csr + row_start[node];
  const __half2* xv = (const __half2*)x;
  float2 a0 = {0.f, 0.f}, a1 = {0.f, 0.f}, a2 = {0.f, 0.f}, a3 = {0.f, 0.f};
  float2 a4 = {0.f, 0.f}, a5 = {0.f, 0.f}, a6 = {0.f, 0.f}, a7 = {0.f, 0.f};
  for (int c0 = 0; c0 < n; c0 += 64) {
    int nn = n - c0; if (nn > 64) nn = 64;
    int sl = (lane < nn) ? bk[c0 + lane] : 0;
    int j = 0;
    for (; j + 8 <= nn; j += 8) {
      int s0 = __shfl(sl, j + 0), s1 = __shfl(sl, j + 1);
      int s2 = __shfl(sl, j + 2), s3 = __shfl(sl, j + 3);
      int s4 = __shfl(sl, j + 4), s5 = __shfl(sl, j + 5);
      int s6 = __shfl(sl, j + 6), s7 = __shfl(sl, j + 7);
      float2 v0 = __half22float2(xv[(size_t)s0 * 64 + lane]);
      float2 v1 = __half22float2(xv[(size_t)s1 * 64 + lane]);
      float2 v2 = __half22float2(xv[(size_t)s2 * 64 + lane]);
      float2 v3 = __half22float2(xv[(size_t)s3 * 64 + lane]);
      float2 v4 = __half22float2(xv[(size_t)s4 * 64 + lane]);
      float2 v5 = __half22float2(xv[(size_t)s5 * 64 + lane]);
      float2 v6 = __half22float2(xv[(size_t)s6 * 64 + lane]);
      float2 v7 = __half22float2(xv[(size_t)s7 * 64 + lane]);
      a0.x += v0.x; a0.y += v0.y;
      a1.x += v1.x; a1.y += v1.y;
      a2.x += v2.x; a2.y += v2.y;
      a3.x += v3.x; a3.y += v3.y;
      a4.x += v4.x; a4.y += v4.y;
      a5.x += v5.x; a5.y += v5.y;
      a6.x += v6.x; a6.y += v6.y;
      a7.x += v7.x; a7.y += v7.y;
    }
    for (; j + 4 <= nn; j += 4) {
      int s0 = __shfl(sl, j + 0), s1 = __shfl(sl, j + 1);
      int s2 = __shfl(sl, j + 2), s3 = __shfl(sl, j + 3);
      float2 v0 = __half22float2(xv[(size_t)s0 * 64 + lane]);
      float2 v1 = __half22float2(xv[(size_t)s1 * 64 + lane]);
      float2 v2 = __half22float2(xv[(size_t)s2 * 64 + lane]);
      float2 v3 = __half22float2(xv[(size_t)s3 * 64 + lane]);
      a0.x += v0.x; a0.y += v0.y;
      a1.x += v1.x; a1.y += v1.y;
      a2.x += v2.x; a2.y += v2.y;
      a3.x += v3.x; a3.y += v3.y;
    }
    for (; j < nn; ++j) {
      int s0 = __shfl(sl, j);
      float2 v0 = __half22float2(xv[(size_t)s0 * 64 + lane]);
      a0.x += v0.x; a0.y += v0.y;
    }
  }
  a0.x += a1.x + a2.x + a3.x + a4.x + a5.x + a6.x + a7.x;
  a0.y += a1.y + a2.y + a3.y + a4.y + a5.y + a6.y + a7.y;
  agg[(size_t)node * 64 + lane] = __floats2half2_rn(a0.x, a0.y);
}

// ---- layer-1 MFMA GEMM + fused layer-2 projection ----
// A in fp16 (agg output); W split keeps W precision: acc = A·W_hi + A·W_lo.
// h1 = relu(in_norm*(A@W1) + b1) in registers; p[row] = out_norm*(h1@W2c).
__global__ __launch_bounds__(256, 4) void k_gemm1(
    const __half* __restrict__ A, const float* __restrict__ in_norm,
    const float* __restrict__ out_norm,
    const _Float16* __restrict__ Whi, const _Float16* __restrict__ Wlo,
    const float* __restrict__ bias, const float* __restrict__ W2c,
    float2* __restrict__ p) {
  int tid = threadIdx.x;
  int wid = tid >> 6, lane = tid & 63;
  int row0 = blockIdx.x * 64 + wid * 16;
  int ar = row0 + (lane & 15);
  bool rv = ar < NN;
  f16x8 a_[4];
#pragma unroll
  for (int kk = 0; kk < 4; ++kk) {
    if (rv) {
      a_[kk] = *(const f16x8*)((const _Float16*)A + (size_t)ar * DD + kk * 32 + ((lane >> 4) << 3));
    } else {
      a_[kk] = (f16x8){0, 0, 0, 0, 0, 0, 0, 0};
    }
  }
  f32x4 acc[8];
#pragma unroll
  for (int nt = 0; nt < 8; ++nt) acc[nt] = (f32x4){0.f, 0.f, 0.f, 0.f};
#pragma unroll
  for (int nt = 0; nt < 8; ++nt) {
#pragma unroll
    for (int kk = 0; kk < 4; ++kk) {
      f16x8 bh = *(const f16x8*)&Whi[(((nt * 4 + kk) * 64) + lane) * 8];
      f16x8 bl = *(const f16x8*)&Wlo[(((nt * 4 + kk) * 64) + lane) * 8];
      acc[nt] = __builtin_amdgcn_mfma_f32_16x16x32_f16(a_[kk], bh, acc[nt], 0, 0, 0);
      acc[nt] = __builtin_amdgcn_mfma_f32_16x16x32_f16(a_[kk], bl, acc[nt], 0, 0, 0);
    }
  }
  int r4 = (lane >> 4) * 4;
  int c0 = lane & 15;
  float wc0[8], wc1[8], bv[8];
#pragma unroll
  for (int nt = 0; nt < 8; ++nt) {
    int col = nt * 16 + c0;
    wc0[nt] = W2c[col * 2 + 0];
    wc1[nt] = W2c[col * 2 + 1];
    bv[nt] = bias[col];
  }
#pragma unroll
  for (int reg = 0; reg < 4; ++reg) {
    int row = row0 + r4 + reg;
    float inm = (row < NN) ? in_norm[row] : 0.f;
    float v0 = 0.f, v1 = 0.f;
#pragma unroll
    for (int nt = 0; nt < 8; ++nt) {
      float y = acc[nt][reg] * inm + bv[nt];
      y = fmaxf(y, 0.f);
      v0 += y * wc0[nt];
      v1 += y * wc1[nt];
    }
#pragma unroll
    for (int off = 1; off < 16; off <<= 1) {
      v0 += __shfl_xor(v0, off);
      v1 += __shfl_xor(v1, off);
    }
    if (row < NN && c0 == 0) {
      float onm = out_norm[row];
      p[row] = make_float2(v0 * onm, v1 * onm);
    }
  }
}

// ---- layer-2 aggregation on 2-dim projections: z[i] = in_norm[i] * sum p[nbr] ----
__global__ __launch_bounds__(256) void k_agg2(
    const float2* __restrict__ p, const int* __restrict__ csr,
    const int* __restrict__ row_start, const int* __restrict__ deg_in,
    const float* __restrict__ in_norm, float2* __restrict__ z) {
  int i = blockIdx.x * 256 + threadIdx.x;
  if (i >= NN) return;
  int n = deg_in[i];
  const int* bk = csr + row_start[i];
  float2 s0 = {0.f, 0.f}, s1 = {0.f, 0.f}, s2 = {0.f, 0.f}, s3 = {0.f, 0.f};
  int j = 0;
  for (; j + 4 <= n; j += 4) {
    int i0 = bk[j], i1 = bk[j + 1], i2 = bk[j + 2], i3 = bk[j + 3];
    float2 q0 = p[i0], q1 = p[i1], q2 = p[i2], q3 = p[i3];
    s0.x += q0.x; s0.y += q0.y;
    s1.x += q1.x; s1.y += q1.y;
    s2.x += q2.x; s2.y += q2.y;
    s3.x += q3.x; s3.y += q3.y;
  }
  for (; j < n; ++j) {
    float2 q = p[bk[j]];
    s0.x += q.x; s0.y += q.y;
  }
  s0.x += s1.x + s2.x + s3.x;
  s0.y += s1.y + s2.y + s3.y;
  float inm = in_norm[i];
  z[i] = make_float2(s0.x * inm, s0.y * inm);
}

// ---- pool: one wave per graph; segment-mean of z + zc -> out ----
__global__ __launch_bounds__(256) void k_pool2(
    const float* __restrict__ z, const int* __restrict__ gid,
    const float* __restrict__ zc, float* __restrict__ out) {
  int g = blockIdx.x * 4 + (threadIdx.x >> 6);
  int lane = threadIdx.x & 63;
  if (g >= NG) return;
  int lo, hi;
  { int a = 0, b = NN; while (a < b) { int m = (a + b) >> 1; if (gid[m] < g) a = m + 1; else b = m; } lo = a; }
  { int a = lo, b = NN; while (a < b) { int m = (a + b) >> 1; if (gid[m] <= g) a = m + 1; else b = m; } hi = a; }
  float s = 0.f;
  int col = lane & 1;
  for (int i = lo + (lane >> 1); i < hi; i += 32) s += z[i * 2 + col];
#pragma unroll
  for (int off = 32; off >= 2; off >>= 1) s += __shfl_down(s, off);
  if (lane < 2) {
    int n = hi - lo;
    out[g * 2 + lane] = s / (float)(n > 0 ? n : 1) + zc[lane];
  }
}

extern "C" void kernel_launch(void* const* d_in, const int* in_sizes, int n_in,
                              void* d_out, int out_size, void* d_ws, size_t ws_size,
                              hipStream_t stream) {
  const float* features = (const float*)d_in[0];
  const int* src = (const int*)d_in[1];
  const int* dst = (const int*)d_in[2];
  const int* gid = (const int*)d_in[3];
  const float* W1 = (const float*)d_in[4];
  const float* b1 = (const float*)d_in[5];
  const float* W2 = (const float*)d_in[6];
  const float* b2 = (const float*)d_in[7];
  const float* Wc = (const float*)d_in[8];
  const float* bc = (const float*)d_in[9];
  float* out = (float*)d_out;

  char* ws = (char*)d_ws;
  size_t off = 0;
  auto take = [&](size_t bytes) {
    char* p = ws + off;
    off = (off + bytes + 255) & ~(size_t)255;
    return p;
  };
  int* cur_d      = (int*)take(NSB * 4);
  int* cur_s      = (int*)take(NSB * 4);
  int* deg_in     = (int*)take((size_t)NN * 4);
  float* out_nrm  = (float*)take((size_t)NN * 4);
  float* in_nrm   = (float*)take((size_t)NN * 4);
  int* row_start  = (int*)take((size_t)NN * 4);
  float* pbuf     = (float*)take((size_t)NN * 2 * 4);
  float* zbuf     = (float*)take((size_t)NN * 2 * 4);
  float* w2c      = (float*)take((size_t)DD * 2 * 4);
  float* zc       = (float*)take(2 * 4);
  unsigned long long* byDst = (unsigned long long*)take((size_t)NSB * SBCAP * 8);
  unsigned short* bySrc = (unsigned short*)take((size_t)NSB * SBCAP * 2);
  int* csr        = (int*)take((size_t)NSB * SBCAP * 4);
  __half* xh      = (__half*)take((size_t)NN * DD * 2);
  __half* bufA    = (__half*)take((size_t)NN * DD * 2);
  _Float16* w1hi  = (_Float16*)take((size_t)DD * DD * 2);
  _Float16* w1lo  = (_Float16*)take((size_t)DD * DD * 2);

  hipMemsetAsync(cur_d, 0, NSB * 4, stream);
  hipMemsetAsync(cur_s, 0, NSB * 4, stream);

  // prep: W1 split (blocks 0-7) + W2c (block 8) + edge binning (blocks 9..520)
  k_prep<<<NB1 + 9, 256, 0, stream>>>(
      W1, W2, Wc, b2, bc, w1hi, w1lo, w2c, zc,
      src, dst, cur_d, cur_s, byDst, bySrc);

  // CSR build + degrees + norms (128 blocks: 64 dst-side, 64 src-side)
  k_csr2<<<128, 1024, 0, stream>>>(
      byDst, cur_d, bySrc, cur_s, csr, row_start, deg_in, in_nrm, out_nrm);

  // features -> fp16, pre-scaled by out_norm
  k_f2h<<<(NN * 32 + 255) / 256, 256, 0, stream>>>(
      (const float4*)features, out_nrm, (uint2*)xh, NN * 32);

  // layer 1: agg (fp16 out) -> bufA ; MFMA GEMM + projection -> pbuf
  k_agg<<<(NN + 3) / 4, 256, 0, stream>>>(xh, csr, row_start, deg_in, (__half2*)bufA);
  k_gemm1<<<(NN + 63) / 64, 256, 0, stream>>>(
      bufA, in_nrm, out_nrm, w1hi, w1lo, b1, w2c, (float2*)pbuf);

  // layer 2 (algebraically reduced): 2-dim aggregate + norm -> zbuf
  k_agg2<<<(NN + 255) / 256, 256, 0, stream>>>(
      (const float2*)pbuf, csr, row_start, deg_in, in_nrm, (float2*)zbuf);

  // segment mean-pool (+ b2@Wc + bc)
  k_pool2<<<(NG + 3) / 4, 256, 0, stream>>>(zbuf, gid, zc, out);
}

// Round 18
// 116.272 us; speedup vs baseline: 2.6695x; 1.0130x over previous
//
#include <hip/hip_runtime.h>
#include <hip/hip_fp16.h>

#define NN 50000
#define NE 800000
#define NG 512
#define DD 128
#define NSB 64               // sub-bins == subpartitions
#define SUBN 782             // ceil(NN/NSB)
#define SBCAP 14336          // per-sub-bin capacity
#define NB1 512
#define NI4 (NE / 4)
#define CH4 ((NI4 + NB1 - 1) / NB1)
#define F2HB 6250            // f2h blocks: NN*32/256

typedef __attribute__((ext_vector_type(8))) _Float16 f16x8;
typedef __attribute__((ext_vector_type(4))) float f32x4;
typedef int v4i __attribute__((ext_vector_type(4)));

// ---- zero the bin cursors (replaces two hipMemsetAsync graph nodes) ----
__global__ void k_zero(int* __restrict__ p) {
  p[threadIdx.x] = 0;   // 128 ints: cur_d[64] + cur_s[64] (contiguous)
}

// ---- merged prep: b<8 W1-split | b==8 W2c | 9<=b<521 edge binning | b>=521 f2h ----
__global__ __launch_bounds__(256) void k_prep(
    const float* __restrict__ W1, const float* __restrict__ W2,
    const float* __restrict__ Wc, const float* __restrict__ b2,
    const float* __restrict__ bc,
    _Float16* __restrict__ w1hi, _Float16* __restrict__ w1lo,
    float* __restrict__ w2c, float* __restrict__ zc,
    const int* __restrict__ src, const int* __restrict__ dst,
    int* __restrict__ cur_d, int* __restrict__ cur_s,
    unsigned long long* __restrict__ byDst, unsigned short* __restrict__ bySrc,
    const float4* __restrict__ x, uint2* __restrict__ xh) {
  __shared__ int cntd[4][NSB], cnts[4][NSB], based[NSB], bases[NSB];
  __shared__ int wbd[4][NSB], wbs[4][NSB];
  int b = blockIdx.x;
  int tid = threadIdx.x;
  if (b >= 521) {
    // f2h: features f32 -> fp16 (UNscaled; out_norm applied in k_agg)
    int i = (b - 521) * 256 + tid;      // < NN*32
    float4 v = x[i];
    __half2 a = __floats2half2_rn(v.x, v.y);
    __half2 c = __floats2half2_rn(v.z, v.w);
    uint2 o;
    o.x = *(unsigned int*)&a;
    o.y = *(unsigned int*)&c;
    xh[i] = o;
  } else if (b < 8) {
    // W1 split into MFMA B-fragment order
    int t = b * 256 + tid;
    int lane = t & 63;
    int grp = t >> 6;
    int kk = grp & 3;
    int nt = grp >> 2;
    int kbase = kk * 32 + ((lane >> 4) << 3);
    int c = nt * 16 + (lane & 15);
#pragma unroll
    for (int j = 0; j < 8; ++j) {
      float v = W1[(kbase + j) * DD + c];
      _Float16 h = (_Float16)v;
      w1hi[t * 8 + j] = h;
      w1lo[t * 8 + j] = (_Float16)(v - (float)h);
    }
  } else if (b == 8) {
    // W2c = W2 @ Wc [128][2]; zc = b2 @ Wc + bc [2]
    int row = tid >> 1, cc = tid & 1;
    float s = 0.f;
#pragma unroll 8
    for (int c = 0; c < DD; ++c) s += W2[row * DD + c] * Wc[c * 2 + cc];
    w2c[row * 2 + cc] = s;
    if (tid < 2) {
      float bb = 0.f;
      for (int c = 0; c < DD; ++c) bb += b2[c] * Wc[c * 2 + tid];
      zc[tid] = bb + bc[tid];
    }
  } else {
    // edge binning (chunk b-9), 4-way wave-privatized LDS histograms
    int w = tid >> 6;
    int i0 = (b - 9) * CH4;
    int i1 = i0 + CH4; if (i1 > NI4) i1 = NI4;
    if (tid < NSB) {
#pragma unroll
      for (int ww = 0; ww < 4; ++ww) { cntd[ww][tid] = 0; cnts[ww][tid] = 0; }
    }
    __syncthreads();
    const v4i* s4 = (const v4i*)src;
    const v4i* d4 = (const v4i*)dst;
    for (int i = i0 + tid; i < i1; i += 256) {
      v4i sv = __builtin_nontemporal_load(&s4[i]);
      v4i dv = __builtin_nontemporal_load(&d4[i]);
#pragma unroll
      for (int k = 0; k < 4; ++k) {
        atomicAdd(&cntd[w][dv[k] / SUBN], 1);
        atomicAdd(&cnts[w][sv[k] / SUBN], 1);
      }
    }
    __syncthreads();
    if (tid < NSB) {
      int run = 0;
#pragma unroll
      for (int ww = 0; ww < 4; ++ww) { wbd[ww][tid] = run; run += cntd[ww][tid]; }
      based[tid] = atomicAdd(&cur_d[tid], run);
#pragma unroll
      for (int ww = 0; ww < 4; ++ww) cntd[ww][tid] = 0;
    } else if (tid < 2 * NSB) {
      int q = tid - NSB;
      int run = 0;
#pragma unroll
      for (int ww = 0; ww < 4; ++ww) { wbs[ww][q] = run; run += cnts[ww][q]; }
      bases[q] = atomicAdd(&cur_s[q], run);
#pragma unroll
      for (int ww = 0; ww < 4; ++ww) cnts[ww][q] = 0;
    }
    __syncthreads();
    for (int i = i0 + tid; i < i1; i += 256) {
      v4i sv = __builtin_nontemporal_load(&s4[i]);
      v4i dv = __builtin_nontemporal_load(&d4[i]);
#pragma unroll
      for (int k = 0; k < 4; ++k) {
        int d = dv[k], s = sv[k];
        int bd = d / SUBN;
        int pd = based[bd] + wbd[w][bd] + atomicAdd(&cntd[w][bd], 1);
        if (pd < SBCAP) byDst[(size_t)bd * SBCAP + pd] = ((unsigned long long)(unsigned)d << 32) | (unsigned)s;
        int bs = s / SUBN;
        int ps = bases[bs] + wbs[w][bs] + atomicAdd(&cnts[w][bs], 1);
        if (ps < SBCAP) bySrc[(size_t)bs * SBCAP + ps] = (unsigned short)(s - bs * SUBN);
      }
    }
  }
}

// ---- merged P2: blocks 0-63 dst-side (CSR + deg_in + in_norm),
//                 blocks 64-127 src-side (out_norm). No global atomics. ----
__global__ __launch_bounds__(1024) void k_csr2(
    const unsigned long long* __restrict__ byDst, const int* __restrict__ cur_d,
    const unsigned short* __restrict__ bySrc, const int* __restrict__ cur_s,
    int* __restrict__ csr, int* __restrict__ row_start, int* __restrict__ deg_in,
    float* __restrict__ in_norm, float* __restrict__ out_norm) {
  __shared__ int hist[SUBN];
  __shared__ int wsum[16];
  int b = blockIdx.x;
  int tid = threadIdx.x;
  if (b < 64) {
    int q = b;
    int nlo = q * SUBN;
    int nhi = nlo + SUBN; if (nhi > NN) nhi = NN;
    int nloc = nhi - nlo;
    for (int i = tid; i < SUBN; i += 1024) hist[i] = 0;
    __syncthreads();
    int m = cur_d[q];
    if (m > SBCAP) m = SBCAP;
    const unsigned long long* bine = byDst + (size_t)q * SBCAP;
    for (int i = tid; i < m; i += 1024) {
      int l = (int)(bine[i] >> 32) - nlo;
      if (l >= 0 && l < nloc) atomicAdd(&hist[l], 1);
    }
    __syncthreads();
    int v = (tid < SUBN) ? hist[tid] : 0;
    int incl = v;
    int lane = tid & 63;
#pragma unroll
    for (int off = 1; off < 64; off <<= 1) {
      int t2 = __shfl_up(incl, off);
      if (lane >= off) incl += t2;
    }
    int wid = tid >> 6;
    if (lane == 63) wsum[wid] = incl;
    __syncthreads();
    if (tid == 0) {
      int run = 0;
      for (int i = 0; i < 16; ++i) { int t = wsum[i]; wsum[i] = run; run += t; }
    }
    __syncthreads();
    int excl = incl - v + wsum[wid];
    if (tid < nloc) {
      deg_in[nlo + tid] = v;
      row_start[nlo + tid] = q * SBCAP + excl;
      in_norm[nlo + tid] = v > 0 ? rsqrtf((float)v) : 0.f;
    }
    __syncthreads();
    if (tid < SUBN) hist[tid] = excl;   // scatter cursor
    __syncthreads();
    for (int i = tid; i < m; i += 1024) {
      unsigned long long p = bine[i];
      int l = (int)(p >> 32) - nlo;
      if (l >= 0 && l < nloc) {
        int pos = atomicAdd(&hist[l], 1);
        if (pos < SBCAP) csr[(size_t)q * SBCAP + pos] = (int)(unsigned)p;
      }
    }
  } else {
    int q = b - 64;
    int nlo = q * SUBN;
    int nhi = nlo + SUBN; if (nhi > NN) nhi = NN;
    int nloc = nhi - nlo;
    for (int i = tid; i < SUBN; i += 1024) hist[i] = 0;
    __syncthreads();
    int m = cur_s[q];
    if (m > SBCAP) m = SBCAP;
    const unsigned short* bine = bySrc + (size_t)q * SBCAP;
    for (int i = tid; i < m; i += 1024) {
      atomicAdd(&hist[bine[i]], 1);
    }
    __syncthreads();
    for (int i = tid; i < nloc; i += 1024) {
      int od = hist[i];
      out_norm[nlo + i] = od > 0 ? rsqrtf((float)od) : 0.f;
    }
  }
}

// ---- aggregation (layer 1): one wave per dst node, fp16 gather weighted by
// out_norm[s] (gathered per edge, shfl-broadcast), f32 accumulate, 8-deep MLP.
// OUTPUT fp16. ----
__global__ __launch_bounds__(256) void k_agg(
    const __half* __restrict__ x, const int* __restrict__ csr,
    const int* __restrict__ row_start, const int* __restrict__ deg_in,
    const float* __restrict__ out_norm, __half2* __restrict__ agg) {
  int node = blockIdx.x * 4 + (threadIdx.x >> 6);
  int lane = threadIdx.x & 63;
  if (node >= NN) return;
  int n = deg_in[node];
  const int* bk = csr + row_start[node];
  const __half2* xv = (const __half2*)x;
  float2 a0 = {0.f, 0.f}, a1 = {0.f, 0.f}, a2 = {0.f, 0.f}, a3 = {0.f, 0.f};
  float2 a4 = {0.f, 0.f}, a5 = {0.f, 0.f}, a6 = {0.f, 0.f}, a7 = {0.f, 0.f};
  for (int c0 = 0; c0 < n; c0 += 64) {
    int nn = n - c0; if (nn > 64) nn = 64;
    int sl = 0; float wl = 0.f;
    if (lane < nn) { sl = bk[c0 + lane]; wl = out_norm[sl]; }
    int j = 0;
    for (; j + 8 <= nn; j += 8) {
      int s0 = __shfl(sl, j + 0), s1 = __shfl(sl, j + 1);
      int s2 = __shfl(sl, j + 2), s3 = __shfl(sl, j + 3);
      int s4 = __shfl(sl, j + 4), s5 = __shfl(sl, j + 5);
      int s6 = __shfl(sl, j + 6), s7 = __shfl(sl, j + 7);
      float w0 = __shfl(wl, j + 0), w1 = __shfl(wl, j + 1);
      float w2 = __shfl(wl, j + 2), w3 = __shfl(wl, j + 3);
      float w4 = __shfl(wl, j + 4), w5 = __shfl(wl, j + 5);
      float w6 = __shfl(wl, j + 6), w7 = __shfl(wl, j + 7);
      float2 v0 = __half22float2(xv[(size_t)s0 * 64 + lane]);
      float2 v1 = __half22float2(xv[(size_t)s1 * 64 + lane]);
      float2 v2 = __half22float2(xv[(size_t)s2 * 64 + lane]);
      float2 v3 = __half22float2(xv[(size_t)s3 * 64 + lane]);
      float2 v4 = __half22float2(xv[(size_t)s4 * 64 + lane]);
      float2 v5 = __half22float2(xv[(size_t)s5 * 64 + lane]);
      float2 v6 = __half22float2(xv[(size_t)s6 * 64 + lane]);
      float2 v7 = __half22float2(xv[(size_t)s7 * 64 + lane]);
      a0.x += v0.x * w0; a0.y += v0.y * w0;
      a1.x += v1.x * w1; a1.y += v1.y * w1;
      a2.x += v2.x * w2; a2.y += v2.y * w2;
      a3.x += v3.x * w3; a3.y += v3.y * w3;
      a4.x += v4.x * w4; a4.y += v4.y * w4;
      a5.x += v5.x * w5; a5.y += v5.y * w5;
      a6.x += v6.x * w6; a6.y += v6.y * w6;
      a7.x += v7.x * w7; a7.y += v7.y * w7;
    }
    for (; j < nn; ++j) {
      int s0 = __shfl(sl, j);
      float w0 = __shfl(wl, j);
      float2 v0 = __half22float2(xv[(size_t)s0 * 64 + lane]);
      a0.x += v0.x * w0; a0.y += v0.y * w0;
    }
  }
  a0.x += a1.x + a2.x + a3.x + a4.x + a5.x + a6.x + a7.x;
  a0.y += a1.y + a2.y + a3.y + a4.y + a5.y + a6.y + a7.y;
  agg[(size_t)node * 64 + lane] = __floats2half2_rn(a0.x, a0.y);
}

// ---- layer-1 MFMA GEMM + fused layer-2 projection ----
// A fp16; W split keeps W precision: acc = A·W_hi + A·W_lo.
// h1 = relu(in_norm*(A@W1) + b1) in registers; p[row] = out_norm*(h1@W2c).
__global__ __launch_bounds__(256, 4) void k_gemm1(
    const __half* __restrict__ A, const float* __restrict__ in_norm,
    const float* __restrict__ out_norm,
    const _Float16* __restrict__ Whi, const _Float16* __restrict__ Wlo,
    const float* __restrict__ bias, const float* __restrict__ W2c,
    float2* __restrict__ p) {
  int tid = threadIdx.x;
  int wid = tid >> 6, lane = tid & 63;
  int row0 = blockIdx.x * 64 + wid * 16;
  int ar = row0 + (lane & 15);
  bool rv = ar < NN;
  f16x8 a_[4];
#pragma unroll
  for (int kk = 0; kk < 4; ++kk) {
    if (rv) {
      a_[kk] = *(const f16x8*)((const _Float16*)A + (size_t)ar * DD + kk * 32 + ((lane >> 4) << 3));
    } else {
      a_[kk] = (f16x8){0, 0, 0, 0, 0, 0, 0, 0};
    }
  }
  f32x4 acc[8];
#pragma unroll
  for (int nt = 0; nt < 8; ++nt) acc[nt] = (f32x4){0.f, 0.f, 0.f, 0.f};
#pragma unroll
  for (int nt = 0; nt < 8; ++nt) {
#pragma unroll
    for (int kk = 0; kk < 4; ++kk) {
      f16x8 bh = *(const f16x8*)&Whi[(((nt * 4 + kk) * 64) + lane) * 8];
      f16x8 bl = *(const f16x8*)&Wlo[(((nt * 4 + kk) * 64) + lane) * 8];
      acc[nt] = __builtin_amdgcn_mfma_f32_16x16x32_f16(a_[kk], bh, acc[nt], 0, 0, 0);
      acc[nt] = __builtin_amdgcn_mfma_f32_16x16x32_f16(a_[kk], bl, acc[nt], 0, 0, 0);
    }
  }
  int r4 = (lane >> 4) * 4;
  int c0 = lane & 15;
  float wc0[8], wc1[8], bv[8];
#pragma unroll
  for (int nt = 0; nt < 8; ++nt) {
    int col = nt * 16 + c0;
    wc0[nt] = W2c[col * 2 + 0];
    wc1[nt] = W2c[col * 2 + 1];
    bv[nt] = bias[col];
  }
#pragma unroll
  for (int reg = 0; reg < 4; ++reg) {
    int row = row0 + r4 + reg;
    float inm = (row < NN) ? in_norm[row] : 0.f;
    float v0 = 0.f, v1 = 0.f;
#pragma unroll
    for (int nt = 0; nt < 8; ++nt) {
      float y = acc[nt][reg] * inm + bv[nt];
      y = fmaxf(y, 0.f);
      v0 += y * wc0[nt];
      v1 += y * wc1[nt];
    }
#pragma unroll
    for (int off = 1; off < 16; off <<= 1) {
      v0 += __shfl_xor(v0, off);
      v1 += __shfl_xor(v1, off);
    }
    if (row < NN && c0 == 0) {
      float onm = out_norm[row];
      p[row] = make_float2(v0 * onm, v1 * onm);
    }
  }
}

// ---- layer-2 aggregation on 2-dim projections: z[i] = in_norm[i] * sum p[nbr] ----
__global__ __launch_bounds__(256) void k_agg2(
    const float2* __restrict__ p, const int* __restrict__ csr,
    const int* __restrict__ row_start, const int* __restrict__ deg_in,
    const float* __restrict__ in_norm, float2* __restrict__ z) {
  int i = blockIdx.x * 256 + threadIdx.x;
  if (i >= NN) return;
  int n = deg_in[i];
  const int* bk = csr + row_start[i];
  float2 s0 = {0.f, 0.f}, s1 = {0.f, 0.f}, s2 = {0.f, 0.f}, s3 = {0.f, 0.f};
  int j = 0;
  for (; j + 4 <= n; j += 4) {
    int i0 = bk[j], i1 = bk[j + 1], i2 = bk[j + 2], i3 = bk[j + 3];
    float2 q0 = p[i0], q1 = p[i1], q2 = p[i2], q3 = p[i3];
    s0.x += q0.x; s0.y += q0.y;
    s1.x += q1.x; s1.y += q1.y;
    s2.x += q2.x; s2.y += q2.y;
    s3.x += q3.x; s3.y += q3.y;
  }
  for (; j < n; ++j) {
    float2 q = p[bk[j]];
    s0.x += q.x; s0.y += q.y;
  }
  s0.x += s1.x + s2.x + s3.x;
  s0.y += s1.y + s2.y + s3.y;
  float inm = in_norm[i];
  z[i] = make_float2(s0.x * inm, s0.y * inm);
}

// ---- pool: one wave per graph; segment-mean of z + zc -> out ----
__global__ __launch_bounds__(256) void k_pool2(
    const float* __restrict__ z, const int* __restrict__ gid,
    const float* __restrict__ zc, float* __restrict__ out) {
  int g = blockIdx.x * 4 + (threadIdx.x >> 6);
  int lane = threadIdx.x & 63;
  if (g >= NG) return;
  int lo, hi;
  { int a = 0, b = NN; while (a < b) { int m = (a + b) >> 1; if (gid[m] < g) a = m + 1; else b = m; } lo = a; }
  { int a = lo, b = NN; while (a < b) { int m = (a + b) >> 1; if (gid[m] <= g) a = m + 1; else b = m; } hi = a; }
  float s = 0.f;
  int col = lane & 1;
  for (int i = lo + (lane >> 1); i < hi; i += 32) s += z[i * 2 + col];
#pragma unroll
  for (int off = 32; off >= 2; off >>= 1) s += __shfl_down(s, off);
  if (lane < 2) {
    int n = hi - lo;
    out[g * 2 + lane] = s / (float)(n > 0 ? n : 1) + zc[lane];
  }
}

extern "C" void kernel_launch(void* const* d_in, const int* in_sizes, int n_in,
                              void* d_out, int out_size, void* d_ws, size_t ws_size,
                              hipStream_t stream) {
  const float* features = (const float*)d_in[0];
  const int* src = (const int*)d_in[1];
  const int* dst = (const int*)d_in[2];
  const int* gid = (const int*)d_in[3];
  const float* W1 = (const float*)d_in[4];
  const float* b1 = (const float*)d_in[5];
  const float* W2 = (const float*)d_in[6];
  const float* b2 = (const float*)d_in[7];
  const float* Wc = (const float*)d_in[8];
  const float* bc = (const float*)d_in[9];
  float* out = (float*)d_out;

  char* ws = (char*)d_ws;
  size_t off = 0;
  auto take = [&](size_t bytes) {
    char* p = ws + off;
    off = (off + bytes + 255) & ~(size_t)255;
    return p;
  };
  int* cur_d      = (int*)take(NSB * 4);   // cur_d at +0, cur_s at +256 B (contiguous ints 0..127)
  int* cur_s      = (int*)take(NSB * 4);
  int* deg_in     = (int*)take((size_t)NN * 4);
  float* out_nrm  = (float*)take((size_t)NN * 4);
  float* in_nrm   = (float*)take((size_t)NN * 4);
  int* row_start  = (int*)take((size_t)NN * 4);
  float* pbuf     = (float*)take((size_t)NN * 2 * 4);
  float* zbuf     = (float*)take((size_t)NN * 2 * 4);
  float* w2c      = (float*)take((size_t)DD * 2 * 4);
  float* zc       = (float*)take(2 * 4);
  unsigned long long* byDst = (unsigned long long*)take((size_t)NSB * SBCAP * 8);
  unsigned short* bySrc = (unsigned short*)take((size_t)NSB * SBCAP * 2);
  int* csr        = (int*)take((size_t)NSB * SBCAP * 4);
  __half* xh      = (__half*)take((size_t)NN * DD * 2);
  __half* bufA    = (__half*)take((size_t)NN * DD * 2);
  _Float16* w1hi  = (_Float16*)take((size_t)DD * DD * 2);
  _Float16* w1lo  = (_Float16*)take((size_t)DD * DD * 2);

  // zero bin cursors (one tiny kernel instead of two memset nodes)
  k_zero<<<1, 128, 0, stream>>>(cur_d);

  // prep: W1 split + W2c + edge binning + f2h (merged; f2h no longer needs norms)
  k_prep<<<521 + F2HB, 256, 0, stream>>>(
      W1, W2, Wc, b2, bc, w1hi, w1lo, w2c, zc,
      src, dst, cur_d, cur_s, byDst, bySrc,
      (const float4*)features, (uint2*)xh);

  // CSR build + degrees + norms (128 blocks: 64 dst-side, 64 src-side)
  k_csr2<<<128, 1024, 0, stream>>>(
      byDst, cur_d, bySrc, cur_s, csr, row_start, deg_in, in_nrm, out_nrm);

  // layer 1: agg (weighted gather, fp16 out) -> bufA ; MFMA GEMM + projection -> pbuf
  k_agg<<<(NN + 3) / 4, 256, 0, stream>>>(
      xh, csr, row_start, deg_in, out_nrm, (__half2*)bufA);
  k_gemm1<<<(NN + 63) / 64, 256, 0, stream>>>(
      bufA, in_nrm, out_nrm, w1hi, w1lo, b1, w2c, (float2*)pbuf);

  // layer 2 (algebraically reduced): 2-dim aggregate + norm -> zbuf
  k_agg2<<<(NN + 255) / 256, 256, 0, stream>>>(
      (const float2*)pbuf, csr, row_start, deg_in, in_nrm, (float2*)zbuf);

  // segment mean-pool (+ b2@Wc + bc)
  k_pool2<<<(NG + 3) / 4, 256, 0, stream>>>(zbuf, gid, zc, out);
}